// Round 7
// baseline (978.553 us; speedup 1.0000x reference)
//
#include <hip/hip_runtime.h>
#include <stdint.h>

#define HID 128

typedef __attribute__((ext_vector_type(8))) short bf16x8;
typedef __attribute__((ext_vector_type(4))) float f32x4;

__device__ __forceinline__ float bf2f(unsigned short u){
  union { unsigned int i; float f; } x; x.i = ((unsigned int)u) << 16; return x.f;
}
__device__ __forceinline__ unsigned short f2bf(float f){
  union { float f; unsigned int i; } x; x.f = f;
  unsigned int b = x.i;
  return (unsigned short)((b + 0x7fffu + ((b >> 16) & 1u)) >> 16);
}

// ---------------- prep: dtype flag + weight conversion + x->bf16, one kernel ----------
struct CvList {
  const void* src[16];
  float* dst[16];
  int cnt[16];
  int n;
};
__global__ __launch_bounds__(256) void prep(CvList L, const void* x,
                                            unsigned short* xc, int n4,
                                            int* __restrict__ dflag){
  __shared__ int red[4];
  int tid = threadIdx.x;
  const unsigned short* xs = (const unsigned short*)x;
  unsigned short u = xs[tid];
  int ex = (u >> 7) & 0xFF;
  int v = ((((tid & 1) == 0) && u == 0) ? 1 : 0) | ((ex >= 140) ? 65536 : 0);
  #pragma unroll
  for (int m = 1; m < 64; m <<= 1) v += __shfl_xor(v, m);
  if ((tid & 63) == 0) red[tid >> 6] = v;
  __syncthreads();
  int tot = red[0] + red[1] + red[2] + red[3];
  bool isf32 = ((tot & 0xffff) >= 32) || ((tot >> 16) >= 8);
  if (blockIdx.x == 0 && tid == 0) dflag[0] = isf32 ? 1 : 0;
  // weights -> fp32
  for (int a = 0; a < L.n; ++a){
    const void* s = L.src[a];
    float* d = L.dst[a];
    int c = L.cnt[a];
    for (int i = blockIdx.x*256 + tid; i < c; i += gridDim.x*256)
      d[i] = isf32 ? ((const float*)s)[i] : bf2f(((const unsigned short*)s)[i]);
  }
  // x -> bf16 (quads)
  for (int i = blockIdx.x*256 + tid; i < n4; i += gridDim.x*256){
    if (isf32){
      float4 q = ((const float4*)x)[i];
      ushort4 o; o.x = f2bf(q.x); o.y = f2bf(q.y); o.z = f2bf(q.z); o.w = f2bf(q.w);
      ((ushort4*)xc)[i] = o;
    } else {
      ((ushort4*)xc)[i] = ((const ushort4*)x)[i];
    }
  }
}

// ---------------- precompute M = W_bond @ (W_edge @ att_edge), cbias = b_bond @ ve ----
__global__ __launch_bounds__(256) void precompute_M(
    const float* __restrict__ We, const float* __restrict__ ae,
    const float* __restrict__ Wb, const float* __restrict__ bb,
    float* __restrict__ Mout, float* __restrict__ cb)
{
  __shared__ float ve[128*12];
  int tid = threadIdx.x;
  for (int i = tid; i < 128*12; i += 256){
    int c = i / 12, lh = i % 12; int l = lh >> 2, h = lh & 3;
    float s = 0.f;
    for (int d = 0; d < 32; ++d)
      s += We[l*16384 + c*128 + h*32 + d] * ae[l*128 + h*32 + d];
    ve[i] = s;
  }
  __syncthreads();
  for (int i = tid; i < 16*12; i += 256){
    int k = i / 12, lh = i % 12;
    float s = 0.f;
    for (int c = 0; c < 128; ++c) s += Wb[k*128 + c] * ve[c*12 + lh];
    Mout[i] = s;
  }
  for (int i = tid; i < 12; i += 256){
    float s = 0.f;
    for (int c = 0; c < 128; ++c) s += bb[c] * ve[c*12 + i];
    cb[i] = s;
  }
}

// ---------------- CSR build ----------------
__global__ __launch_bounds__(256) void deg_count(const int* __restrict__ ei, int E, int* __restrict__ deg){
  int e = blockIdx.x*256 + threadIdx.x;
  if (e < E) atomicAdd(&deg[ei[E + e]], 1);
}
__global__ __launch_bounds__(256) void scan_part(const int* __restrict__ deg, int* __restrict__ part, int N){
  int base = blockIdx.x*1024;
  int s = 0;
  for (int i = threadIdx.x; i < 1024; i += 256){ int j = base + i; if (j < N) s += deg[j]; }
  __shared__ int sh[256];
  sh[threadIdx.x] = s; __syncthreads();
  for (int m = 128; m > 0; m >>= 1){ if (threadIdx.x < m) sh[threadIdx.x] += sh[threadIdx.x + m]; __syncthreads(); }
  if (threadIdx.x == 0) part[blockIdx.x] = sh[0];
}
__global__ void scan_top(int* part, int P){
  if (threadIdx.x == 0 && blockIdx.x == 0){
    int acc = 0;
    for (int i = 0; i < P; ++i){ int v = part[i]; part[i] = acc; acc += v; }
  }
}
__global__ __launch_bounds__(256) void scan_write(const int* __restrict__ deg, const int* __restrict__ part,
                                                  int* __restrict__ row, int N, int E){
  int base = blockIdx.x*1024 + threadIdx.x*4;
  int v0=0,v1=0,v2=0,v3=0;
  if (base+0 < N) v0 = deg[base+0];
  if (base+1 < N) v1 = deg[base+1];
  if (base+2 < N) v2 = deg[base+2];
  if (base+3 < N) v3 = deg[base+3];
  int s = v0+v1+v2+v3;
  __shared__ int sh[256];
  sh[threadIdx.x] = s; __syncthreads();
  for (int m = 1; m < 256; m <<= 1){
    int t = (threadIdx.x >= m) ? sh[threadIdx.x - m] : 0;
    __syncthreads();
    sh[threadIdx.x] += t;
    __syncthreads();
  }
  int excl = sh[threadIdx.x] - s + part[blockIdx.x];
  if (base+0 < N) row[base+0] = excl; excl += v0;
  if (base+1 < N) row[base+1] = excl; excl += v1;
  if (base+2 < N) row[base+2] = excl; excl += v2;
  if (base+3 < N) row[base+3] = excl;
  if (blockIdx.x == 0 && threadIdx.x == 0) row[N] = E;
}
// CSR fill + edge_attr reorder in ONE 64 B record scatter per edge:
// rec[idx] (4×uint4): [0..1]=eattr as 16×bf16, [2].x=src, [2].y=dst
__global__ __launch_bounds__(256) void csr_fill(const int* __restrict__ ei, int E,
                                                const int* __restrict__ row, int* __restrict__ cursor,
                                                const void* __restrict__ eattr,
                                                uint4* __restrict__ rec, const int* __restrict__ flag){
  int e = blockIdx.x*256 + threadIdx.x;
  if (e >= E) return;
  int s = ei[e], d = ei[E + e];
  uint4 q0, q1;
  if (flag[0]){
    const float4* pp = (const float4*)((const float*)eattr + (size_t)e*16);
    float4 a = pp[0], b = pp[1], c = pp[2], dd = pp[3];
    q0.x = f2bf(a.x) | ((unsigned)f2bf(a.y) << 16);
    q0.y = f2bf(a.z) | ((unsigned)f2bf(a.w) << 16);
    q0.z = f2bf(b.x) | ((unsigned)f2bf(b.y) << 16);
    q0.w = f2bf(b.z) | ((unsigned)f2bf(b.w) << 16);
    q1.x = f2bf(c.x) | ((unsigned)f2bf(c.y) << 16);
    q1.y = f2bf(c.z) | ((unsigned)f2bf(c.w) << 16);
    q1.z = f2bf(dd.x) | ((unsigned)f2bf(dd.y) << 16);
    q1.w = f2bf(dd.z) | ((unsigned)f2bf(dd.w) << 16);
  } else {
    const uint4* pp = (const uint4*)((const unsigned short*)eattr + (size_t)e*16);
    q0 = pp[0]; q1 = pp[1];
  }
  int pos = atomicAdd(&cursor[d], 1);
  size_t idx = (size_t)(row[d] + pos);
  uint4* rp = rec + idx*4;
  rp[0] = q0;
  rp[1] = q1;
  uint4 q2; q2.x = (unsigned)s; q2.y = (unsigned)d; q2.z = 0u; q2.w = 0u;
  rp[2] = q2;
}

__device__ __forceinline__ float lrelu(float x){ return x > 0.f ? x : 0.2f*x; }
__device__ __forceinline__ float expg(float x){ return __expf(fminf(x, 0.f)); }

// ---------------- MFMA GEMM: out[N,128] = A[N,K](bf16) @ W[K,128] (+bias) ----------------
// OUTMODE: 0 = bf16 out, 1 = external out (flag: 1=fp32, 0=bf16), 2 = dual fp32 + bf16
// EPI: fused attention scores a_src/a_dst
template<int K, int OUTMODE, bool EPI>
__global__ __launch_bounds__(256) void mfma_lin(const unsigned short* __restrict__ A,
                                                const float* __restrict__ W,
                                                const float* __restrict__ bias,
                                                void* __restrict__ Out, void* __restrict__ Out2,
                                                int N, const int* __restrict__ flag,
                                                const float* __restrict__ attS,
                                                const float* __restrict__ attD,
                                                float* __restrict__ a_src,
                                                float* __restrict__ a_dst)
{
  constexpr int KP = K + 8;
  __shared__ unsigned short WT[128*KP];
  __shared__ float sAs[128], sAd[128];
  int tid = threadIdx.x;
  for (int i = tid; i < K*128; i += 256){
    int k = i >> 7, ch = i & 127;
    WT[ch*KP + k] = f2bf(W[i]);
  }
  if (EPI && tid < 128){ sAs[tid] = attS[tid]; sAd[tid] = attD[tid]; }
  __syncthreads();
  int wid = tid >> 6, lane = tid & 63;
  int quad = lane >> 4, m = lane & 15;
  int nodeBase = blockIdx.x*64 + wid*16;
  int node = nodeBase + m;
  int nodeC = (node < N) ? node : 0;
  bf16x8 afr[K/32];
  #pragma unroll
  for (int kb = 0; kb < K/32; ++kb)
    afr[kb] = *(const bf16x8*)(A + (size_t)nodeC*K + kb*32 + quad*8);
  f32x4 acc[8] = {};
  #pragma unroll
  for (int t = 0; t < 8; ++t){
    #pragma unroll
    for (int kb = 0; kb < K/32; ++kb){
      bf16x8 bfr = *(const bf16x8*)&WT[(t*16 + m)*KP + kb*32 + quad*8];
      acc[t] = __builtin_amdgcn_mfma_f32_16x16x32_bf16(afr[kb], bfr, acc[t], 0, 0, 0);
    }
  }
  bool f32out = (OUTMODE == 1) && (flag[0] != 0);
  #pragma unroll
  for (int t = 0; t < 8; ++t){
    int ch = t*16 + m;
    float bv = bias ? bias[ch] : 0.f;
    #pragma unroll
    for (int r2 = 0; r2 < 4; ++r2){
      int nd = nodeBase + quad*4 + r2;
      if (nd < N){
        float v = acc[t][r2] + bv;
        if (OUTMODE == 0){
          ((unsigned short*)Out)[(size_t)nd*HID + ch] = f2bf(v);
        } else if (OUTMODE == 2){
          ((float*)Out)[(size_t)nd*HID + ch] = v;
          ((unsigned short*)Out2)[(size_t)nd*HID + ch] = f2bf(v);
        } else {
          if (f32out) ((float*)Out)[(size_t)nd*HID + ch] = v;
          else        ((unsigned short*)Out)[(size_t)nd*HID + ch] = f2bf(v);
        }
      }
    }
  }
  if (EPI){
    #pragma unroll
    for (int r2 = 0; r2 < 4; ++r2){
      float vs[4], vd[4];
      #pragma unroll
      for (int h = 0; h < 4; ++h){
        int c0 = (2*h)*16 + m, c1 = (2*h+1)*16 + m;
        vs[h] = acc[2*h][r2]*sAs[c0] + acc[2*h+1][r2]*sAs[c1];
        vd[h] = acc[2*h][r2]*sAd[c0] + acc[2*h+1][r2]*sAd[c1];
      }
      #pragma unroll
      for (int mm = 1; mm < 16; mm <<= 1){
        #pragma unroll
        for (int h = 0; h < 4; ++h){
          vs[h] += __shfl_xor(vs[h], mm);
          vd[h] += __shfl_xor(vd[h], mm);
        }
      }
      if (m == 0){
        int nd = nodeBase + quad*4 + r2;
        if (nd < N){
          float4 vsv, vdv;
          vsv.x=vs[0]; vsv.y=vs[1]; vsv.z=vs[2]; vsv.w=vs[3];
          vdv.x=vd[0]; vdv.y=vd[1]; vdv.z=vd[2]; vdv.w=vd[3];
          *(float4*)(a_src + (size_t)nd*4) = vsv;
          *(float4*)(a_dst + (size_t)nd*4) = vdv;
        }
      }
    }
  }
}

// ---------------- fused BN + ReLU + residual + GEMM (+EPI / external out) -------------
// OUTMODE 0: internal bf16 xh out + EPI; OUTMODE 1: external out per flag, no EPI
template<int OUTMODE, bool WRITEH>
__global__ __launch_bounds__(256) void bn_mfma(const float* __restrict__ hg,
                                               const float* __restrict__ hprev,
                                               const float* __restrict__ bnsum,
                                               const float* __restrict__ bnsq,
                                               const float* __restrict__ gamma,
                                               const float* __restrict__ beta,
                                               const float* __restrict__ W,
                                               const float* __restrict__ bias,
                                               void* __restrict__ Out,
                                               float* __restrict__ hout,
                                               int N, const int* __restrict__ flag,
                                               const float* __restrict__ attS,
                                               const float* __restrict__ attD,
                                               float* __restrict__ a_src,
                                               float* __restrict__ a_dst)
{
  constexpr int K = 128, KP = 136;
  __shared__ unsigned short WT[128*KP];
  __shared__ float sSc[128], sSh[128];
  __shared__ float sAs[128], sAd[128];
  int tid = threadIdx.x;
  for (int i = tid; i < K*128; i += 256){
    int k = i >> 7, ch = i & 127;
    WT[ch*KP + k] = f2bf(W[i]);
  }
  if (tid < 128){
    float mean = bnsum[tid] / (float)N;
    float var  = fmaxf(bnsq[tid] / (float)N - mean*mean, 0.f);
    float sc = gamma[tid] * rsqrtf(var + 1e-5f);
    sSc[tid] = sc;
    sSh[tid] = beta[tid] - mean*sc;
    if (OUTMODE == 0){ sAs[tid] = attS[tid]; sAd[tid] = attD[tid]; }
  }
  __syncthreads();
  int wid = tid >> 6, lane = tid & 63;
  int quad = lane >> 4, m = lane & 15;
  int nodeBase = blockIdx.x*64 + wid*16;
  int node = nodeBase + m;
  int nodeC = (node < N) ? node : 0;
  bf16x8 afr[4];
  #pragma unroll
  for (int kb = 0; kb < 4; ++kb){
    int cbase = kb*32 + quad*8;
    const float4* gp = (const float4*)(hg + (size_t)nodeC*K + cbase);
    const float4* pp = (const float4*)(hprev + (size_t)nodeC*K + cbase);
    float4 g0 = gp[0], g1 = gp[1], p0 = pp[0], p1 = pp[1];
    float r[8];
    float gv[8] = {g0.x,g0.y,g0.z,g0.w,g1.x,g1.y,g1.z,g1.w};
    float pv[8] = {p0.x,p0.y,p0.z,p0.w,p1.x,p1.y,p1.z,p1.w};
    #pragma unroll
    for (int j = 0; j < 8; ++j){
      float t = gv[j]*sSc[cbase+j] + sSh[cbase+j];
      t = t > 0.f ? t : 0.f;
      r[j] = t + pv[j];
    }
    if (WRITEH && node < N){
      float4 o0, o1;
      o0.x=r[0]; o0.y=r[1]; o0.z=r[2]; o0.w=r[3];
      o1.x=r[4]; o1.y=r[5]; o1.z=r[6]; o1.w=r[7];
      float4* hp = (float4*)(hout + (size_t)node*K + cbase);
      hp[0] = o0; hp[1] = o1;
    }
    bf16x8 f;
    #pragma unroll
    for (int j = 0; j < 8; ++j) f[j] = (short)f2bf(r[j]);
    afr[kb] = f;
  }
  f32x4 acc[8] = {};
  #pragma unroll
  for (int t = 0; t < 8; ++t){
    #pragma unroll
    for (int kb = 0; kb < 4; ++kb){
      bf16x8 bfr = *(const bf16x8*)&WT[(t*16 + m)*KP + kb*32 + quad*8];
      acc[t] = __builtin_amdgcn_mfma_f32_16x16x32_bf16(afr[kb], bfr, acc[t], 0, 0, 0);
    }
  }
  bool f32out = (OUTMODE == 1) && (flag[0] != 0);
  #pragma unroll
  for (int t = 0; t < 8; ++t){
    int ch = t*16 + m;
    float bv = bias ? bias[ch] : 0.f;
    #pragma unroll
    for (int r2 = 0; r2 < 4; ++r2){
      int nd = nodeBase + quad*4 + r2;
      if (nd < N){
        float v = acc[t][r2] + bv;
        if (OUTMODE == 0) ((unsigned short*)Out)[(size_t)nd*HID + ch] = f2bf(v);
        else if (f32out)  ((float*)Out)[(size_t)nd*HID + ch] = v;
        else              ((unsigned short*)Out)[(size_t)nd*HID + ch] = f2bf(v);
      }
    }
  }
  if (OUTMODE == 0){
    #pragma unroll
    for (int r2 = 0; r2 < 4; ++r2){
      float vs[4], vd[4];
      #pragma unroll
      for (int h = 0; h < 4; ++h){
        int c0 = (2*h)*16 + m, c1 = (2*h+1)*16 + m;
        vs[h] = acc[2*h][r2]*sAs[c0] + acc[2*h+1][r2]*sAs[c1];
        vd[h] = acc[2*h][r2]*sAd[c0] + acc[2*h+1][r2]*sAd[c1];
      }
      #pragma unroll
      for (int mm = 1; mm < 16; mm <<= 1){
        #pragma unroll
        for (int h = 0; h < 4; ++h){
          vs[h] += __shfl_xor(vs[h], mm);
          vd[h] += __shfl_xor(vd[h], mm);
        }
      }
      if (m == 0){
        int nd = nodeBase + quad*4 + r2;
        if (nd < N){
          float4 vsv, vdv;
          vsv.x=vs[0]; vsv.y=vs[1]; vsv.z=vs[2]; vsv.w=vs[3];
          vdv.x=vd[0]; vdv.y=vd[1]; vdv.z=vd[2]; vdv.w=vd[3];
          *(float4*)(a_src + (size_t)nd*4) = vsv;
          *(float4*)(a_dst + (size_t)nd*4) = vdv;
        }
      }
    }
  }
}

// ---------------- edge-parallel alpha + per-dst ae accumulation ----------------
__global__ __launch_bounds__(256) void edge_alpha(
    const uint4* __restrict__ rec,
    const float* __restrict__ a_src, const float* __restrict__ a_dst,
    const float* __restrict__ Mmat, const float* __restrict__ cbias,
    float4* __restrict__ alphaA, int* __restrict__ srcA,
    float* __restrict__ aeSum, int E, int layer)
{
  __shared__ float sM[16][4];
  __shared__ float sC[4];
  int tid = threadIdx.x;
  if (tid < 64) sM[tid>>2][tid&3] = Mmat[(tid>>2)*12 + layer*4 + (tid&3)];
  if (tid < 4)  sC[tid] = cbias[layer*4 + tid];
  __syncthreads();
  int pos = blockIdx.x*256 + tid;
  if (pos >= E) return;
  const uint4* rp = rec + (size_t)pos*4;
  uint4 u0 = rp[0], u1 = rp[1], u2 = rp[2];
  int src = (int)u2.x, dst = (int)u2.y;
  unsigned w[8] = {u0.x,u0.y,u0.z,u0.w,u1.x,u1.y,u1.z,u1.w};
  float a0 = sC[0], a1 = sC[1], a2 = sC[2], a3 = sC[3];
  #pragma unroll
  for (int k = 0; k < 16; ++k){
    float v = bf2f((unsigned short)((k & 1) ? (w[k>>1] >> 16) : (w[k>>1] & 0xffffu)));
    a0 += v*sM[k][0]; a1 += v*sM[k][1]; a2 += v*sM[k][2]; a3 += v*sM[k][3];
  }
  float* as = aeSum + (size_t)dst*4;
  atomicAdd(as + 0, a0); atomicAdd(as + 1, a1);
  atomicAdd(as + 2, a2); atomicAdd(as + 3, a3);
  float4 as4 = *(const float4*)(a_src + (size_t)src*4);
  float4 ad4 = *(const float4*)(a_dst + (size_t)dst*4);
  float4 al;
  al.x = lrelu(as4.x + ad4.x + a0);
  al.y = lrelu(as4.y + ad4.y + a1);
  al.z = lrelu(as4.z + ad4.z + a2);
  al.w = lrelu(as4.w + ad4.w + a3);
  alphaA[pos] = al;
  srcA[pos] = src;
}

// ---------------- GAT aggregation: wave/node, contiguous alpha, bf16 gathers ----
__global__ __launch_bounds__(256) void gat_agg(
    const unsigned short* __restrict__ xh, const float4* __restrict__ alphaA,
    const int* __restrict__ srcA, const int* __restrict__ row,
    const float* __restrict__ a_src, const float* __restrict__ a_dst,
    const float* __restrict__ aeSum, const float* __restrict__ cb,
    const float* __restrict__ bconv, float* __restrict__ hout, int N, int layer)
{
  __shared__ float sPf[4][256];   // [wave][e*4+h]  (conflict-free reads)
  __shared__ int   sOff[4][64];
  int tid = threadIdx.x;
  int wid = tid >> 6, lane = tid & 63;
  int n = blockIdx.x*4 + wid;
  int nn = (n < N) ? n : 0;
  int r = row[nn];
  int deg = row[nn+1] - r;
  if (n >= N) deg = 0;

  float4 aL; aL.x = aL.y = aL.z = aL.w = -1e30f;
  int mysrc = 0;
  if (lane < deg){
    aL = alphaA[r + lane];
    mysrc = srcA[r + lane];
  }
  float mx0 = aL.x, mx1 = aL.y, mx2 = aL.z, mx3 = aL.w;
  for (int e = lane + 64; e < deg; e += 64){   // rare
    float4 t = alphaA[r + e];
    mx0 = fmaxf(mx0, t.x); mx1 = fmaxf(mx1, t.y);
    mx2 = fmaxf(mx2, t.z); mx3 = fmaxf(mx3, t.w);
  }
  #pragma unroll
  for (int m = 1; m < 64; m <<= 1){
    mx0 = fmaxf(mx0, __shfl_xor(mx0,m)); mx1 = fmaxf(mx1, __shfl_xor(mx1,m));
    mx2 = fmaxf(mx2, __shfl_xor(mx2,m)); mx3 = fmaxf(mx3, __shfl_xor(mx3,m));
  }
  // self-loop alpha from aeSum (mean of incoming ae; deg==0 -> cbias)
  float4 asn = *(const float4*)(a_src + (size_t)nn*4);
  float4 adn = *(const float4*)(a_dst + (size_t)nn*4);
  float4 aes = *(const float4*)(aeSum + (size_t)nn*4);
  float invd = (deg > 0) ? 1.0f/(float)deg : 0.0f;
  float e0 = (deg > 0) ? aes.x*invd : cb[0];
  float e1 = (deg > 0) ? aes.y*invd : cb[1];
  float e2 = (deg > 0) ? aes.z*invd : cb[2];
  float e3 = (deg > 0) ? aes.w*invd : cb[3];
  float f0 = lrelu(asn.x + adn.x + e0);
  float f1 = lrelu(asn.y + adn.y + e1);
  float f2 = lrelu(asn.z + adn.z + e2);
  float f3 = lrelu(asn.w + adn.w + e3);
  mx0 = fmaxf(mx0, f0); mx1 = fmaxf(mx1, f1);
  mx2 = fmaxf(mx2, f2); mx3 = fmaxf(mx3, f3);

  float p0 = 0.f, p1 = 0.f, p2 = 0.f, p3 = 0.f;
  if (lane < deg){
    p0 = expg(aL.x-mx0); p1 = expg(aL.y-mx1);
    p2 = expg(aL.z-mx2); p3 = expg(aL.w-mx3);
  }
  float4 pv; pv.x = p0; pv.y = p1; pv.z = p2; pv.w = p3;
  *(float4*)&sPf[wid][lane*4] = pv;
  sOff[wid][lane] = mysrc << 8;   // src * 256 B (bf16 row)
  float d0 = p0, d1 = p1, d2 = p2, d3 = p3;
  for (int e = lane + 64; e < deg; e += 64){   // rare
    float4 t = alphaA[r + e];
    d0 += expg(t.x-mx0); d1 += expg(t.y-mx1);
    d2 += expg(t.z-mx2); d3 += expg(t.w-mx3);
  }
  #pragma unroll
  for (int m = 1; m < 64; m <<= 1){
    d0 += __shfl_xor(d0,m); d1 += __shfl_xor(d1,m); d2 += __shfl_xor(d2,m); d3 += __shfl_xor(d3,m);
  }
  float ps0 = expg(f0-mx0), ps1 = expg(f1-mx1), ps2 = expg(f2-mx2), ps3 = expg(f3-mx3);
  float i0 = 1.0f/(d0+ps0+1e-16f), i1 = 1.0f/(d1+ps1+1e-16f);
  float i2 = 1.0f/(d2+ps2+1e-16f), i3 = 1.0f/(d3+ps3+1e-16f);

  // gather: lane covers channels 2*lane, 2*lane+1; head h = lane>>4
  int h = lane >> 4;
  float psh = h==0 ? ps0 : h==1 ? ps1 : h==2 ? ps2 : ps3;
  float ih  = h==0 ? i0  : h==1 ? i1  : h==2 ? i2  : i3;
  float mxh = h==0 ? mx0 : h==1 ? mx1 : h==2 ? mx2 : mx3;
  const char* xb = (const char*)xh;
  float acc0 = 0.f, acc1 = 0.f;
  int dmin = deg < 64 ? deg : 64;
  int e = 0;
  for (; e + 4 <= dmin; e += 4){
    int oA = sOff[wid][e+0], oB = sOff[wid][e+1], oC = sOff[wid][e+2], oD = sOff[wid][e+3];
    float qA = sPf[wid][(e+0)*4 + h], qB = sPf[wid][(e+1)*4 + h];
    float qC = sPf[wid][(e+2)*4 + h], qD = sPf[wid][(e+3)*4 + h];
    ushort2 xA = *(const ushort2*)(xb + (size_t)oA + lane*4);
    ushort2 xB = *(const ushort2*)(xb + (size_t)oB + lane*4);
    ushort2 xC = *(const ushort2*)(xb + (size_t)oC + lane*4);
    ushort2 xD = *(const ushort2*)(xb + (size_t)oD + lane*4);
    acc0 += qA*bf2f(xA.x) + qB*bf2f(xB.x) + qC*bf2f(xC.x) + qD*bf2f(xD.x);
    acc1 += qA*bf2f(xA.y) + qB*bf2f(xB.y) + qC*bf2f(xC.y) + qD*bf2f(xD.y);
  }
  for (; e < dmin; ++e){
    int o = sOff[wid][e];
    float q = sPf[wid][e*4 + h];
    ushort2 xv = *(const ushort2*)(xb + (size_t)o + lane*4);
    acc0 += q*bf2f(xv.x); acc1 += q*bf2f(xv.y);
  }
  for (; e < deg; ++e){            // rare (deg>64)
    float4 t = alphaA[r + e];
    float av = h==0 ? t.x : h==1 ? t.y : h==2 ? t.z : t.w;
    float q = expg(av - mxh);
    int s = srcA[r + e];
    ushort2 xv = *(const ushort2*)(xb + (size_t)s*256 + lane*4);
    acc0 += q*bf2f(xv.x); acc1 += q*bf2f(xv.y);
  }
  if (n < N){
    ushort2 xn = *(const ushort2*)(xb + (size_t)nn*256 + lane*4);
    acc0 += psh * bf2f(xn.x);
    acc1 += psh * bf2f(xn.y);
    float2 bc = *(const float2*)(bconv + layer*128 + 2*lane);
    acc0 = acc0*ih + bc.x;
    acc1 = acc1*ih + bc.y;
    float2 o; o.x = acc0; o.y = acc1;
    *(float2*)(hout + (size_t)nn*128 + 2*lane) = o;
  }
}

// ---------------- batch norm stats ----------------
__global__ __launch_bounds__(256) void bn_stats(const float* __restrict__ h, float* __restrict__ sum,
                                                float* __restrict__ sq, int N){
  int c = threadIdx.x & 127;
  int sub = threadIdx.x >> 7;
  float s = 0.f, q = 0.f;
  for (int n = blockIdx.x*2 + sub; n < N; n += gridDim.x*2){
    float v = h[(size_t)n*128 + c];
    s += v; q += v*v;
  }
  __shared__ float ls[256], lq[256];
  ls[threadIdx.x] = s; lq[threadIdx.x] = q;
  __syncthreads();
  if (threadIdx.x < 128){
    s = ls[threadIdx.x] + ls[threadIdx.x + 128];
    q = lq[threadIdx.x] + lq[threadIdx.x + 128];
    atomicAdd(&sum[c], s);
    atomicAdd(&sq[c], q);
  }
}

// ---------------- host ----------------
extern "C" void kernel_launch(void* const* d_in, const int* in_sizes, int n_in,
                              void* d_out, int out_size, void* d_ws, size_t ws_size,
                              hipStream_t stream)
{
  const void* x        = d_in[0];
  const int*  ei       = (const int*)d_in[1];
  const void* eattr    = d_in[2];
  int N = in_sizes[0] / 64;
  int E = in_sizes[1] / 2;

  char* p = (char*)d_ws;
  auto alloc = [&](size_t bytes)->char* {
    char* r = p; p += (bytes + 255) & ~(size_t)255; return r;
  };
  // zero-region first (one memset)
  int*   deg    = (int*)alloc((size_t)N*4);
  int*   cursor = (int*)alloc((size_t)N*4);
  float* bnsum  = (float*)alloc(3*128*4);
  float* bnsq   = (float*)alloc(3*128*4);
  float* aeSum  = (float*)alloc((size_t)3*N*4*4);
  size_t zbytes = (size_t)(p - (char*)deg);
  int*   dflag  = (int*)alloc(256);
  int*   row    = (int*)alloc(((size_t)N + 1)*4);
  int*   part   = (int*)alloc(1024*4);
  uint4* rec    = (uint4*)alloc((size_t)E*64);
  int*   srcA   = (int*)alloc((size_t)E*4);
  float4* alphaA= (float4*)alloc((size_t)E*16);
  float* hA     = (float*)alloc((size_t)N*128*4);
  float* hB     = (float*)alloc((size_t)N*128*4);
  float* hG     = (float*)alloc((size_t)N*128*4);
  unsigned short* hAb = (unsigned short*)alloc((size_t)N*128*2);
  unsigned short* xhb = (unsigned short*)alloc((size_t)N*128*2);
  float* a_src  = (float*)alloc((size_t)N*4*4);
  float* a_dst  = (float*)alloc((size_t)N*4*4);
  float* Mmat   = (float*)alloc(16*12*4);
  float* cbias  = (float*)alloc(12*4);
  unsigned short* xc  = (unsigned short*)alloc((size_t)N*64*2);
  float* wc     = (float*)alloc(130000*4);

  // canonical weight buffers (fp32)
  int   woff[14] = {0, 8192, 8320, 10368, 10496, 59648, 108800, 109184,
                    109568, 109952, 110336, 110720, 111104, 127488};
  int   wcnt[14] = {8192, 128, 2048, 128, 49152, 49152, 384, 384, 384, 384, 384, 384, 16384, 128};
  CvList L; L.n = 14;
  for (int a = 0; a < 14; ++a){ L.src[a] = d_in[3+a]; L.dst[a] = wc + woff[a]; L.cnt[a] = wcnt[a]; }
  float* cW_atom = wc + woff[0];  float* cb_atom = wc + woff[1];
  float* cW_bond = wc + woff[2];  float* cb_bond = wc + woff[3];
  float* cW_lin  = wc + woff[4];  float* cW_edge = wc + woff[5];
  float* catt_s  = wc + woff[6];  float* catt_d  = wc + woff[7];
  float* catt_e  = wc + woff[8];  float* cbconv  = wc + woff[9];
  float* cgamma  = wc + woff[10]; float* cbeta   = wc + woff[11];
  float* cW_out  = wc + woff[12]; float* cb_out  = wc + woff[13];

  hipMemsetAsync(deg, 0, zbytes, stream);
  prep<<<256, 256, 0, stream>>>(L, x, xc, N*16, dflag);
  precompute_M<<<1, 256, 0, stream>>>(cW_edge, catt_e, cW_bond, cb_bond, Mmat, cbias);
  deg_count<<<(E + 255)/256, 256, 0, stream>>>(ei, E, deg);
  int P = (N + 1023)/1024;
  scan_part<<<P, 256, 0, stream>>>(deg, part, N);
  scan_top<<<1, 64, 0, stream>>>(part, P);
  scan_write<<<P, 256, 0, stream>>>(deg, part, row, N, E);
  csr_fill<<<(E + 255)/256, 256, 0, stream>>>(ei, E, row, cursor, eattr, rec, dflag);

  // atom embedding: hA(fp32) + hAb(bf16) = x @ W_atom + b_atom
  mfma_lin<64, 2, false><<<(N + 63)/64, 256, 0, stream>>>(xc, cW_atom, cb_atom, hA, hAb, N, dflag,
      nullptr, nullptr, nullptr, nullptr);
  // layer-0 GEMM + attention scores
  mfma_lin<128, 0, true><<<(N + 63)/64, 256, 0, stream>>>(hAb, cW_lin, nullptr, xhb, nullptr, N, dflag,
      catt_s, catt_d, a_src, a_dst);

  float* cur = hA; float* oth = hB;
  for (int l = 0; l < 3; ++l){
    edge_alpha<<<(E + 255)/256, 256, 0, stream>>>(rec, a_src, a_dst, Mmat, cbias,
                                                  alphaA, srcA, aeSum + (size_t)l*N*4, E, l);
    gat_agg<<<(N + 3)/4, 256, 0, stream>>>(xhb, alphaA, srcA, row, a_src, a_dst,
                                           aeSum + (size_t)l*N*4, cbias + l*4,
                                           cbconv, hG, N, l);
    bn_stats<<<256, 256, 0, stream>>>(hG, bnsum + l*128, bnsq + l*128, N);
    if (l < 2){
      bn_mfma<0, true><<<(N + 63)/64, 256, 0, stream>>>(hG, cur,
          bnsum + l*128, bnsq + l*128, cgamma + l*128, cbeta + l*128,
          cW_lin + (size_t)(l+1)*16384, nullptr, xhb, oth, N, dflag,
          catt_s + (l+1)*128, catt_d + (l+1)*128, a_src, a_dst);
      float* t = cur; cur = oth; oth = t;
    } else {
      bn_mfma<1, false><<<(N + 63)/64, 256, 0, stream>>>(hG, cur,
          bnsum + l*128, bnsq + l*128, cgamma + l*128, cbeta + l*128,
          cW_out, cb_out, d_out, nullptr, N, dflag,
          nullptr, nullptr, nullptr, nullptr);
    }
  }
}

// Round 8
// 615.263 us; speedup vs baseline: 1.5905x; 1.5905x over previous
//
#include <hip/hip_runtime.h>
#include <stdint.h>

#define HID 128

typedef __attribute__((ext_vector_type(8))) short bf16x8;
typedef __attribute__((ext_vector_type(4))) float f32x4;

__device__ __forceinline__ float bf2f(unsigned short u){
  union { unsigned int i; float f; } x; x.i = ((unsigned int)u) << 16; return x.f;
}
__device__ __forceinline__ unsigned short f2bf(float f){
  union { float f; unsigned int i; } x; x.f = f;
  unsigned int b = x.i;
  return (unsigned short)((b + 0x7fffu + ((b >> 16) & 1u)) >> 16);
}

// ---------------- prep: dtype flag + weight conversion + x->bf16, one kernel ----------
struct CvList {
  const void* src[16];
  float* dst[16];
  int cnt[16];
  int n;
};
__global__ __launch_bounds__(256) void prep(CvList L, const void* x,
                                            unsigned short* xc, int n4,
                                            int* __restrict__ dflag){
  __shared__ int red[4];
  int tid = threadIdx.x;
  const unsigned short* xs = (const unsigned short*)x;
  unsigned short u = xs[tid];
  int ex = (u >> 7) & 0xFF;
  int v = ((((tid & 1) == 0) && u == 0) ? 1 : 0) | ((ex >= 140) ? 65536 : 0);
  #pragma unroll
  for (int m = 1; m < 64; m <<= 1) v += __shfl_xor(v, m);
  if ((tid & 63) == 0) red[tid >> 6] = v;
  __syncthreads();
  int tot = red[0] + red[1] + red[2] + red[3];
  bool isf32 = ((tot & 0xffff) >= 32) || ((tot >> 16) >= 8);
  if (blockIdx.x == 0 && tid == 0) dflag[0] = isf32 ? 1 : 0;
  // weights -> fp32
  for (int a = 0; a < L.n; ++a){
    const void* s = L.src[a];
    float* d = L.dst[a];
    int c = L.cnt[a];
    for (int i = blockIdx.x*256 + tid; i < c; i += gridDim.x*256)
      d[i] = isf32 ? ((const float*)s)[i] : bf2f(((const unsigned short*)s)[i]);
  }
  // x -> bf16 (quads)
  for (int i = blockIdx.x*256 + tid; i < n4; i += gridDim.x*256){
    if (isf32){
      float4 q = ((const float4*)x)[i];
      ushort4 o; o.x = f2bf(q.x); o.y = f2bf(q.y); o.z = f2bf(q.z); o.w = f2bf(q.w);
      ((ushort4*)xc)[i] = o;
    } else {
      ((ushort4*)xc)[i] = ((const ushort4*)x)[i];
    }
  }
}

// ---------------- precompute M = W_bond @ (W_edge @ att_edge), cbias = b_bond @ ve ----
__global__ __launch_bounds__(256) void precompute_M(
    const float* __restrict__ We, const float* __restrict__ ae,
    const float* __restrict__ Wb, const float* __restrict__ bb,
    float* __restrict__ Mout, float* __restrict__ cb)
{
  __shared__ float ve[128*12];
  int tid = threadIdx.x;
  for (int i = tid; i < 128*12; i += 256){
    int c = i / 12, lh = i % 12; int l = lh >> 2, h = lh & 3;
    float s = 0.f;
    for (int d = 0; d < 32; ++d)
      s += We[l*16384 + c*128 + h*32 + d] * ae[l*128 + h*32 + d];
    ve[i] = s;
  }
  __syncthreads();
  for (int i = tid; i < 16*12; i += 256){
    int k = i / 12, lh = i % 12;
    float s = 0.f;
    for (int c = 0; c < 128; ++c) s += Wb[k*128 + c] * ve[c*12 + lh];
    Mout[i] = s;
  }
  for (int i = tid; i < 12; i += 256){
    float s = 0.f;
    for (int c = 0; c < 128; ++c) s += bb[c] * ve[c*12 + i];
    cb[i] = s;
  }
}

// ---------------- CSR build ----------------
__global__ __launch_bounds__(256) void deg_count(const int* __restrict__ ei, int E, int* __restrict__ deg){
  int e = blockIdx.x*256 + threadIdx.x;
  if (e < E) atomicAdd(&deg[ei[E + e]], 1);
}
__global__ __launch_bounds__(256) void scan_part(const int* __restrict__ deg, int* __restrict__ part, int N){
  int base = blockIdx.x*1024;
  int s = 0;
  for (int i = threadIdx.x; i < 1024; i += 256){ int j = base + i; if (j < N) s += deg[j]; }
  __shared__ int sh[256];
  sh[threadIdx.x] = s; __syncthreads();
  for (int m = 128; m > 0; m >>= 1){ if (threadIdx.x < m) sh[threadIdx.x] += sh[threadIdx.x + m]; __syncthreads(); }
  if (threadIdx.x == 0) part[blockIdx.x] = sh[0];
}
__global__ void scan_top(int* part, int P){
  if (threadIdx.x == 0 && blockIdx.x == 0){
    int acc = 0;
    for (int i = 0; i < P; ++i){ int v = part[i]; part[i] = acc; acc += v; }
  }
}
__global__ __launch_bounds__(256) void scan_write(const int* __restrict__ deg, const int* __restrict__ part,
                                                  int* __restrict__ row, int N, int E){
  int base = blockIdx.x*1024 + threadIdx.x*4;
  int v0=0,v1=0,v2=0,v3=0;
  if (base+0 < N) v0 = deg[base+0];
  if (base+1 < N) v1 = deg[base+1];
  if (base+2 < N) v2 = deg[base+2];
  if (base+3 < N) v3 = deg[base+3];
  int s = v0+v1+v2+v3;
  __shared__ int sh[256];
  sh[threadIdx.x] = s; __syncthreads();
  for (int m = 1; m < 256; m <<= 1){
    int t = (threadIdx.x >= m) ? sh[threadIdx.x - m] : 0;
    __syncthreads();
    sh[threadIdx.x] += t;
    __syncthreads();
  }
  int excl = sh[threadIdx.x] - s + part[blockIdx.x];
  if (base+0 < N) row[base+0] = excl; excl += v0;
  if (base+1 < N) row[base+1] = excl; excl += v1;
  if (base+2 < N) row[base+2] = excl; excl += v2;
  if (base+3 < N) row[base+3] = excl;
  if (blockIdx.x == 0 && threadIdx.x == 0) row[N] = E;
}
// CSR fill + edge_attr reorder in ONE 64 B record scatter per edge:
// rec[idx] (4×uint4): [0..1]=eattr as 16×bf16, [2].x=src, [2].y=dst
__global__ __launch_bounds__(256) void csr_fill(const int* __restrict__ ei, int E,
                                                const int* __restrict__ row, int* __restrict__ cursor,
                                                const void* __restrict__ eattr,
                                                uint4* __restrict__ rec, const int* __restrict__ flag){
  int e = blockIdx.x*256 + threadIdx.x;
  if (e >= E) return;
  int s = ei[e], d = ei[E + e];
  uint4 q0, q1;
  if (flag[0]){
    const float4* pp = (const float4*)((const float*)eattr + (size_t)e*16);
    float4 a = pp[0], b = pp[1], c = pp[2], dd = pp[3];
    q0.x = f2bf(a.x) | ((unsigned)f2bf(a.y) << 16);
    q0.y = f2bf(a.z) | ((unsigned)f2bf(a.w) << 16);
    q0.z = f2bf(b.x) | ((unsigned)f2bf(b.y) << 16);
    q0.w = f2bf(b.z) | ((unsigned)f2bf(b.w) << 16);
    q1.x = f2bf(c.x) | ((unsigned)f2bf(c.y) << 16);
    q1.y = f2bf(c.z) | ((unsigned)f2bf(c.w) << 16);
    q1.z = f2bf(dd.x) | ((unsigned)f2bf(dd.y) << 16);
    q1.w = f2bf(dd.z) | ((unsigned)f2bf(dd.w) << 16);
  } else {
    const uint4* pp = (const uint4*)((const unsigned short*)eattr + (size_t)e*16);
    q0 = pp[0]; q1 = pp[1];
  }
  int pos = atomicAdd(&cursor[d], 1);
  size_t idx = (size_t)(row[d] + pos);
  uint4* rp = rec + idx*4;
  rp[0] = q0;
  rp[1] = q1;
  uint4 q2; q2.x = (unsigned)s; q2.y = (unsigned)d; q2.z = 0u; q2.w = 0u;
  rp[2] = q2;
}
// per-node mean of CSR-ordered edge_attr (layer-invariant) from records, + deg indicator
__global__ __launch_bounds__(256) void ea_mean_k(const unsigned int* __restrict__ rec,
                                                 const int* __restrict__ row,
                                                 float* __restrict__ ea_mean,
                                                 float* __restrict__ deg_ind, int N){
  int idx = blockIdx.x*256 + threadIdx.x;
  if (idx >= N*4) return;
  int n = idx >> 2, q = idx & 3;
  int r = row[n], deg = row[n+1] - r;
  float s0=0.f, s1=0.f, s2=0.f, s3=0.f;
  for (int e = 0; e < deg; ++e){
    uint2 u = *(const uint2*)(rec + (size_t)(r+e)*16 + q*2);
    s0 += bf2f((unsigned short)(u.x & 0xffffu)); s1 += bf2f((unsigned short)(u.x >> 16));
    s2 += bf2f((unsigned short)(u.y & 0xffffu)); s3 += bf2f((unsigned short)(u.y >> 16));
  }
  float inv = 1.f / (float)(deg > 0 ? deg : 1);
  float4 o; o.x = s0*inv; o.y = s1*inv; o.z = s2*inv; o.w = s3*inv;
  *(float4*)(ea_mean + (size_t)n*16 + q*4) = o;
  if (q == 0) deg_ind[n] = (deg > 0) ? 1.f : 0.f;
}

__device__ __forceinline__ float lrelu(float x){ return x > 0.f ? x : 0.2f*x; }
__device__ __forceinline__ float expg(float x){ return __expf(fminf(x, 0.f)); }

// shared EPI: attention scores + self-loop alpha, from acc[8] C-fragments
template<typename ACC>
__device__ __forceinline__ void att_epi(const ACC* acc, int m, int quad, int nodeBase, int N,
                                        const float* sAs, const float* sAd,
                                        const float (*sMM)[4], const float* sCB,
                                        const float* __restrict__ ea_mean,
                                        const float* __restrict__ deg_ind,
                                        float* __restrict__ a_src,
                                        float* __restrict__ a_dst,
                                        float* __restrict__ alpha_self)
{
  #pragma unroll
  for (int r2 = 0; r2 < 4; ++r2){
    float vs[4], vd[4];
    #pragma unroll
    for (int h = 0; h < 4; ++h){
      int c0 = (2*h)*16 + m, c1 = (2*h+1)*16 + m;
      vs[h] = acc[2*h][r2]*sAs[c0] + acc[2*h+1][r2]*sAs[c1];
      vd[h] = acc[2*h][r2]*sAd[c0] + acc[2*h+1][r2]*sAd[c1];
    }
    #pragma unroll
    for (int mm = 1; mm < 16; mm <<= 1){
      #pragma unroll
      for (int h = 0; h < 4; ++h){
        vs[h] += __shfl_xor(vs[h], mm);
        vd[h] += __shfl_xor(vd[h], mm);
      }
    }
    if (m == 0){
      int nd = nodeBase + quad*4 + r2;
      if (nd < N){
        float ci = deg_ind[nd];
        const float4* em = (const float4*)(ea_mean + (size_t)nd*16);
        float4 e0 = em[0], e1 = em[1], e2 = em[2], e3 = em[3];
        float ev[16] = {e0.x,e0.y,e0.z,e0.w, e1.x,e1.y,e1.z,e1.w,
                        e2.x,e2.y,e2.z,e2.w, e3.x,e3.y,e3.z,e3.w};
        float aS[4];
        #pragma unroll
        for (int h = 0; h < 4; ++h){
          float d = sCB[h]*ci;
          #pragma unroll
          for (int k = 0; k < 16; ++k) d += ev[k]*sMM[k][h];
          aS[h] = lrelu(vs[h] + vd[h] + d);
        }
        float4 vsv, vdv, asv;
        vsv.x=vs[0]; vsv.y=vs[1]; vsv.z=vs[2]; vsv.w=vs[3];
        vdv.x=vd[0]; vdv.y=vd[1]; vdv.z=vd[2]; vdv.w=vd[3];
        asv.x=aS[0]; asv.y=aS[1]; asv.z=aS[2]; asv.w=aS[3];
        *(float4*)(a_src + (size_t)nd*4) = vsv;
        *(float4*)(a_dst + (size_t)nd*4) = vdv;
        *(float4*)(alpha_self + (size_t)nd*4) = asv;
      }
    }
  }
}

// ---------------- MFMA GEMM: out[N,128] = A[N,K](bf16) @ W[K,128] (+bias) ----------------
// OUTMODE: 0 = bf16 out + EPI, 2 = dual fp32 + bf16 (no EPI)
template<int K, int OUTMODE, bool EPI>
__global__ __launch_bounds__(256) void mfma_lin(const unsigned short* __restrict__ A,
                                                const float* __restrict__ W,
                                                const float* __restrict__ bias,
                                                void* __restrict__ Out, void* __restrict__ Out2,
                                                int N,
                                                const float* __restrict__ attS,
                                                const float* __restrict__ attD,
                                                const float* __restrict__ Ml,   // stride-12 col of Mmat
                                                const float* __restrict__ cbl,
                                                const float* __restrict__ ea_mean,
                                                const float* __restrict__ deg_ind,
                                                float* __restrict__ a_src,
                                                float* __restrict__ a_dst,
                                                float* __restrict__ alpha_self)
{
  constexpr int KP = K + 8;
  __shared__ unsigned short WT[128*KP];
  __shared__ float sAs[128], sAd[128];
  __shared__ float sMM[16][4];
  __shared__ float sCB[4];
  int tid = threadIdx.x;
  for (int i = tid; i < K*128; i += 256){
    int k = i >> 7, ch = i & 127;
    WT[ch*KP + k] = f2bf(W[i]);
  }
  if (EPI){
    if (tid < 128){ sAs[tid] = attS[tid]; sAd[tid] = attD[tid]; }
    if (tid < 64) sMM[tid>>2][tid&3] = Ml[(tid>>2)*12 + (tid&3)];
    if (tid < 4)  sCB[tid] = cbl[tid];
  }
  __syncthreads();
  int wid = tid >> 6, lane = tid & 63;
  int quad = lane >> 4, m = lane & 15;
  int nodeBase = blockIdx.x*64 + wid*16;
  int node = nodeBase + m;
  int nodeC = (node < N) ? node : 0;
  bf16x8 afr[K/32];
  #pragma unroll
  for (int kb = 0; kb < K/32; ++kb)
    afr[kb] = *(const bf16x8*)(A + (size_t)nodeC*K + kb*32 + quad*8);
  f32x4 acc[8] = {};
  #pragma unroll
  for (int t = 0; t < 8; ++t){
    #pragma unroll
    for (int kb = 0; kb < K/32; ++kb){
      bf16x8 bfr = *(const bf16x8*)&WT[(t*16 + m)*KP + kb*32 + quad*8];
      acc[t] = __builtin_amdgcn_mfma_f32_16x16x32_bf16(afr[kb], bfr, acc[t], 0, 0, 0);
    }
  }
  #pragma unroll
  for (int t = 0; t < 8; ++t){
    int ch = t*16 + m;
    float bv = bias ? bias[ch] : 0.f;
    #pragma unroll
    for (int r2 = 0; r2 < 4; ++r2){
      int nd = nodeBase + quad*4 + r2;
      if (nd < N){
        float v = acc[t][r2] + bv;
        if (OUTMODE == 0){
          ((unsigned short*)Out)[(size_t)nd*HID + ch] = f2bf(v);
        } else {
          ((float*)Out)[(size_t)nd*HID + ch] = v;
          ((unsigned short*)Out2)[(size_t)nd*HID + ch] = f2bf(v);
        }
      }
    }
  }
  if (EPI)
    att_epi(acc, m, quad, nodeBase, N, sAs, sAd, sMM, sCB,
            ea_mean, deg_ind, a_src, a_dst, alpha_self);
}

// ---------------- fused BN + ReLU + residual + GEMM (+EPI / external out) -------------
// OUTMODE 0: internal bf16 xh out + EPI + fp32 h out; OUTMODE 1: external out per flag
template<int OUTMODE, bool WRITEH>
__global__ __launch_bounds__(256) void bn_mfma(const float* __restrict__ hg,
                                               const float* __restrict__ hprev,
                                               const float* __restrict__ bnsum,
                                               const float* __restrict__ bnsq,
                                               const float* __restrict__ gamma,
                                               const float* __restrict__ beta,
                                               const float* __restrict__ W,
                                               const float* __restrict__ bias,
                                               void* __restrict__ Out,
                                               float* __restrict__ hout,
                                               int N, const int* __restrict__ flag,
                                               const float* __restrict__ attS,
                                               const float* __restrict__ attD,
                                               const float* __restrict__ Ml,
                                               const float* __restrict__ cbl,
                                               const float* __restrict__ ea_mean,
                                               const float* __restrict__ deg_ind,
                                               float* __restrict__ a_src,
                                               float* __restrict__ a_dst,
                                               float* __restrict__ alpha_self)
{
  constexpr int K = 128, KP = 136;
  __shared__ unsigned short WT[128*KP];
  __shared__ float sSc[128], sSh[128];
  __shared__ float sAs[128], sAd[128];
  __shared__ float sMM[16][4];
  __shared__ float sCB[4];
  int tid = threadIdx.x;
  for (int i = tid; i < K*128; i += 256){
    int k = i >> 7, ch = i & 127;
    WT[ch*KP + k] = f2bf(W[i]);
  }
  if (tid < 128){
    float mean = bnsum[tid] / (float)N;
    float var  = fmaxf(bnsq[tid] / (float)N - mean*mean, 0.f);
    float sc = gamma[tid] * rsqrtf(var + 1e-5f);
    sSc[tid] = sc;
    sSh[tid] = beta[tid] - mean*sc;
    if (OUTMODE == 0){ sAs[tid] = attS[tid]; sAd[tid] = attD[tid]; }
  }
  if (OUTMODE == 0){
    if (tid < 64) sMM[tid>>2][tid&3] = Ml[(tid>>2)*12 + (tid&3)];
    if (tid < 4)  sCB[tid] = cbl[tid];
  }
  __syncthreads();
  int wid = tid >> 6, lane = tid & 63;
  int quad = lane >> 4, m = lane & 15;
  int nodeBase = blockIdx.x*64 + wid*16;
  int node = nodeBase + m;
  int nodeC = (node < N) ? node : 0;
  bf16x8 afr[4];
  #pragma unroll
  for (int kb = 0; kb < 4; ++kb){
    int cbase = kb*32 + quad*8;
    const float4* gp = (const float4*)(hg + (size_t)nodeC*K + cbase);
    const float4* pp = (const float4*)(hprev + (size_t)nodeC*K + cbase);
    float4 g0 = gp[0], g1 = gp[1], p0 = pp[0], p1 = pp[1];
    float r[8];
    float gv[8] = {g0.x,g0.y,g0.z,g0.w,g1.x,g1.y,g1.z,g1.w};
    float pv[8] = {p0.x,p0.y,p0.z,p0.w,p1.x,p1.y,p1.z,p1.w};
    #pragma unroll
    for (int j = 0; j < 8; ++j){
      float t = gv[j]*sSc[cbase+j] + sSh[cbase+j];
      t = t > 0.f ? t : 0.f;
      r[j] = t + pv[j];
    }
    if (WRITEH && node < N){
      float4 o0, o1;
      o0.x=r[0]; o0.y=r[1]; o0.z=r[2]; o0.w=r[3];
      o1.x=r[4]; o1.y=r[5]; o1.z=r[6]; o1.w=r[7];
      float4* hp = (float4*)(hout + (size_t)node*K + cbase);
      hp[0] = o0; hp[1] = o1;
    }
    bf16x8 f;
    #pragma unroll
    for (int j = 0; j < 8; ++j) f[j] = (short)f2bf(r[j]);
    afr[kb] = f;
  }
  f32x4 acc[8] = {};
  #pragma unroll
  for (int t = 0; t < 8; ++t){
    #pragma unroll
    for (int kb = 0; kb < 4; ++kb){
      bf16x8 bfr = *(const bf16x8*)&WT[(t*16 + m)*KP + kb*32 + quad*8];
      acc[t] = __builtin_amdgcn_mfma_f32_16x16x32_bf16(afr[kb], bfr, acc[t], 0, 0, 0);
    }
  }
  bool f32out = (OUTMODE == 1) && (flag[0] != 0);
  #pragma unroll
  for (int t = 0; t < 8; ++t){
    int ch = t*16 + m;
    float bv = bias ? bias[ch] : 0.f;
    #pragma unroll
    for (int r2 = 0; r2 < 4; ++r2){
      int nd = nodeBase + quad*4 + r2;
      if (nd < N){
        float v = acc[t][r2] + bv;
        if (OUTMODE == 0) ((unsigned short*)Out)[(size_t)nd*HID + ch] = f2bf(v);
        else if (f32out)  ((float*)Out)[(size_t)nd*HID + ch] = v;
        else              ((unsigned short*)Out)[(size_t)nd*HID + ch] = f2bf(v);
      }
    }
  }
  if (OUTMODE == 0)
    att_epi(acc, m, quad, nodeBase, N, sAs, sAd, sMM, sCB,
            ea_mean, deg_ind, a_src, a_dst, alpha_self);
}

// ---------------- edge-parallel alpha (coalesced record stream, NO atomics) ----------
__global__ __launch_bounds__(256) void edge_alpha(
    const uint4* __restrict__ rec,
    const float* __restrict__ a_src, const float* __restrict__ a_dst,
    const float* __restrict__ Mmat, const float* __restrict__ cbias,
    float4* __restrict__ alphaA, int* __restrict__ srcA, int E, int layer)
{
  __shared__ float sM[16][4];
  __shared__ float sC[4];
  int tid = threadIdx.x;
  if (tid < 64) sM[tid>>2][tid&3] = Mmat[(tid>>2)*12 + layer*4 + (tid&3)];
  if (tid < 4)  sC[tid] = cbias[layer*4 + tid];
  __syncthreads();
  int pos = blockIdx.x*256 + tid;
  if (pos >= E) return;
  const uint4* rp = rec + (size_t)pos*4;
  uint4 u0 = rp[0], u1 = rp[1], u2 = rp[2];
  int src = (int)u2.x, dst = (int)u2.y;
  unsigned w[8] = {u0.x,u0.y,u0.z,u0.w,u1.x,u1.y,u1.z,u1.w};
  float a0 = sC[0], a1 = sC[1], a2 = sC[2], a3 = sC[3];
  #pragma unroll
  for (int k = 0; k < 16; ++k){
    float v = bf2f((unsigned short)((k & 1) ? (w[k>>1] >> 16) : (w[k>>1] & 0xffffu)));
    a0 += v*sM[k][0]; a1 += v*sM[k][1]; a2 += v*sM[k][2]; a3 += v*sM[k][3];
  }
  float4 as4 = *(const float4*)(a_src + (size_t)src*4);
  float4 ad4 = *(const float4*)(a_dst + (size_t)dst*4);
  float4 al;
  al.x = lrelu(as4.x + ad4.x + a0);
  al.y = lrelu(as4.y + ad4.y + a1);
  al.z = lrelu(as4.z + ad4.z + a2);
  al.w = lrelu(as4.w + ad4.w + a3);
  alphaA[pos] = al;
  srcA[pos] = src;
}

// ---------------- GAT aggregation: wave/node, contiguous alpha, bf16 gathers ----
__global__ __launch_bounds__(256) void gat_agg(
    const unsigned short* __restrict__ xh, const float4* __restrict__ alphaA,
    const int* __restrict__ srcA, const int* __restrict__ row,
    const float4* __restrict__ alpha_self,
    const float* __restrict__ bconv, float* __restrict__ hout, int N, int layer)
{
  __shared__ float sPf[4][256];   // [wave][e*4+h]  (conflict-free reads)
  __shared__ int   sOff[4][64];
  int tid = threadIdx.x;
  int wid = tid >> 6, lane = tid & 63;
  int n = blockIdx.x*4 + wid;
  int nn = (n < N) ? n : 0;
  int r = row[nn];
  int deg = row[nn+1] - r;
  if (n >= N) deg = 0;

  float4 aL; aL.x = aL.y = aL.z = aL.w = -1e30f;
  int mysrc = 0;
  if (lane < deg){
    aL = alphaA[r + lane];
    mysrc = srcA[r + lane];
  }
  float mx0 = aL.x, mx1 = aL.y, mx2 = aL.z, mx3 = aL.w;
  for (int e = lane + 64; e < deg; e += 64){   // rare
    float4 t = alphaA[r + e];
    mx0 = fmaxf(mx0, t.x); mx1 = fmaxf(mx1, t.y);
    mx2 = fmaxf(mx2, t.z); mx3 = fmaxf(mx3, t.w);
  }
  #pragma unroll
  for (int m = 1; m < 64; m <<= 1){
    mx0 = fmaxf(mx0, __shfl_xor(mx0,m)); mx1 = fmaxf(mx1, __shfl_xor(mx1,m));
    mx2 = fmaxf(mx2, __shfl_xor(mx2,m)); mx3 = fmaxf(mx3, __shfl_xor(mx3,m));
  }
  float4 sf = alpha_self[nn];
  mx0 = fmaxf(mx0, sf.x); mx1 = fmaxf(mx1, sf.y);
  mx2 = fmaxf(mx2, sf.z); mx3 = fmaxf(mx3, sf.w);

  float p0 = 0.f, p1 = 0.f, p2 = 0.f, p3 = 0.f;
  if (lane < deg){
    p0 = expg(aL.x-mx0); p1 = expg(aL.y-mx1);
    p2 = expg(aL.z-mx2); p3 = expg(aL.w-mx3);
  }
  float4 pv; pv.x = p0; pv.y = p1; pv.z = p2; pv.w = p3;
  *(float4*)&sPf[wid][lane*4] = pv;
  sOff[wid][lane] = mysrc << 8;   // src * 256 B (bf16 row)
  float d0 = p0, d1 = p1, d2 = p2, d3 = p3;
  for (int e = lane + 64; e < deg; e += 64){   // rare
    float4 t = alphaA[r + e];
    d0 += expg(t.x-mx0); d1 += expg(t.y-mx1);
    d2 += expg(t.z-mx2); d3 += expg(t.w-mx3);
  }
  #pragma unroll
  for (int m = 1; m < 64; m <<= 1){
    d0 += __shfl_xor(d0,m); d1 += __shfl_xor(d1,m); d2 += __shfl_xor(d2,m); d3 += __shfl_xor(d3,m);
  }
  float ps0 = expg(sf.x-mx0), ps1 = expg(sf.y-mx1), ps2 = expg(sf.z-mx2), ps3 = expg(sf.w-mx3);
  float i0 = 1.0f/(d0+ps0+1e-16f), i1 = 1.0f/(d1+ps1+1e-16f);
  float i2 = 1.0f/(d2+ps2+1e-16f), i3 = 1.0f/(d3+ps3+1e-16f);

  // gather: lane covers channels 2*lane, 2*lane+1; head h = lane>>4
  int h = lane >> 4;
  float psh = h==0 ? ps0 : h==1 ? ps1 : h==2 ? ps2 : ps3;
  float ih  = h==0 ? i0  : h==1 ? i1  : h==2 ? i2  : i3;
  float mxh = h==0 ? mx0 : h==1 ? mx1 : h==2 ? mx2 : mx3;
  const char* xb = (const char*)xh;
  float acc0 = 0.f, acc1 = 0.f;
  int dmin = deg < 64 ? deg : 64;
  int e = 0;
  for (; e + 4 <= dmin; e += 4){
    int oA = sOff[wid][e+0], oB = sOff[wid][e+1], oC = sOff[wid][e+2], oD = sOff[wid][e+3];
    float qA = sPf[wid][(e+0)*4 + h], qB = sPf[wid][(e+1)*4 + h];
    float qC = sPf[wid][(e+2)*4 + h], qD = sPf[wid][(e+3)*4 + h];
    ushort2 xA = *(const ushort2*)(xb + (size_t)oA + lane*4);
    ushort2 xB = *(const ushort2*)(xb + (size_t)oB + lane*4);
    ushort2 xC = *(const ushort2*)(xb + (size_t)oC + lane*4);
    ushort2 xD = *(const ushort2*)(xb + (size_t)oD + lane*4);
    acc0 += qA*bf2f(xA.x) + qB*bf2f(xB.x) + qC*bf2f(xC.x) + qD*bf2f(xD.x);
    acc1 += qA*bf2f(xA.y) + qB*bf2f(xB.y) + qC*bf2f(xC.y) + qD*bf2f(xD.y);
  }
  for (; e < dmin; ++e){
    int o = sOff[wid][e];
    float q = sPf[wid][e*4 + h];
    ushort2 xv = *(const ushort2*)(xb + (size_t)o + lane*4);
    acc0 += q*bf2f(xv.x); acc1 += q*bf2f(xv.y);
  }
  for (; e < deg; ++e){            // rare (deg>64)
    float4 t = alphaA[r + e];
    float av = h==0 ? t.x : h==1 ? t.y : h==2 ? t.z : t.w;
    float q = expg(av - mxh);
    int s = srcA[r + e];
    ushort2 xv = *(const ushort2*)(xb + (size_t)s*256 + lane*4);
    acc0 += q*bf2f(xv.x); acc1 += q*bf2f(xv.y);
  }
  if (n < N){
    ushort2 xn = *(const ushort2*)(xb + (size_t)nn*256 + lane*4);
    acc0 += psh * bf2f(xn.x);
    acc1 += psh * bf2f(xn.y);
    float2 bc = *(const float2*)(bconv + layer*128 + 2*lane);
    acc0 = acc0*ih + bc.x;
    acc1 = acc1*ih + bc.y;
    float2 o; o.x = acc0; o.y = acc1;
    *(float2*)(hout + (size_t)nn*128 + 2*lane) = o;
  }
}

// ---------------- batch norm stats ----------------
__global__ __launch_bounds__(256) void bn_stats(const float* __restrict__ h, float* __restrict__ sum,
                                                float* __restrict__ sq, int N){
  int c = threadIdx.x & 127;
  int sub = threadIdx.x >> 7;
  float s = 0.f, q = 0.f;
  for (int n = blockIdx.x*2 + sub; n < N; n += gridDim.x*2){
    float v = h[(size_t)n*128 + c];
    s += v; q += v*v;
  }
  __shared__ float ls[256], lq[256];
  ls[threadIdx.x] = s; lq[threadIdx.x] = q;
  __syncthreads();
  if (threadIdx.x < 128){
    s = ls[threadIdx.x] + ls[threadIdx.x + 128];
    q = lq[threadIdx.x] + lq[threadIdx.x + 128];
    atomicAdd(&sum[c], s);
    atomicAdd(&sq[c], q);
  }
}

// ---------------- host ----------------
extern "C" void kernel_launch(void* const* d_in, const int* in_sizes, int n_in,
                              void* d_out, int out_size, void* d_ws, size_t ws_size,
                              hipStream_t stream)
{
  const void* x        = d_in[0];
  const int*  ei       = (const int*)d_in[1];
  const void* eattr    = d_in[2];
  int N = in_sizes[0] / 64;
  int E = in_sizes[1] / 2;

  char* p = (char*)d_ws;
  auto alloc = [&](size_t bytes)->char* {
    char* r = p; p += (bytes + 255) & ~(size_t)255; return r;
  };
  // zero-region first (one memset)
  int*   deg    = (int*)alloc((size_t)N*4);
  int*   cursor = (int*)alloc((size_t)N*4);
  float* bnsum  = (float*)alloc(3*128*4);
  float* bnsq   = (float*)alloc(3*128*4);
  size_t zbytes = (size_t)(p - (char*)deg);
  int*   dflag  = (int*)alloc(256);
  int*   row    = (int*)alloc(((size_t)N + 1)*4);
  int*   part   = (int*)alloc(1024*4);
  uint4* rec    = (uint4*)alloc((size_t)E*64);
  int*   srcA   = (int*)alloc((size_t)E*4);
  float4* alphaA= (float4*)alloc((size_t)E*16);
  float* hA     = (float*)alloc((size_t)N*128*4);
  float* hB     = (float*)alloc((size_t)N*128*4);
  float* hG     = (float*)alloc((size_t)N*128*4);
  unsigned short* hAb = (unsigned short*)alloc((size_t)N*128*2);
  unsigned short* xhb = (unsigned short*)alloc((size_t)N*128*2);
  float* a_src  = (float*)alloc((size_t)N*4*4);
  float* a_dst  = (float*)alloc((size_t)N*4*4);
  float* alphaS = (float*)alloc((size_t)N*4*4);
  float* ea_mean= (float*)alloc((size_t)N*16*4);
  float* deg_ind= (float*)alloc((size_t)N*4);
  float* Mmat   = (float*)alloc(16*12*4);
  float* cbias  = (float*)alloc(12*4);
  unsigned short* xc  = (unsigned short*)alloc((size_t)N*64*2);
  float* wc     = (float*)alloc(130000*4);

  // canonical weight buffers (fp32)
  int   woff[14] = {0, 8192, 8320, 10368, 10496, 59648, 108800, 109184,
                    109568, 109952, 110336, 110720, 111104, 127488};
  int   wcnt[14] = {8192, 128, 2048, 128, 49152, 49152, 384, 384, 384, 384, 384, 384, 16384, 128};
  CvList L; L.n = 14;
  for (int a = 0; a < 14; ++a){ L.src[a] = d_in[3+a]; L.dst[a] = wc + woff[a]; L.cnt[a] = wcnt[a]; }
  float* cW_atom = wc + woff[0];  float* cb_atom = wc + woff[1];
  float* cW_bond = wc + woff[2];  float* cb_bond = wc + woff[3];
  float* cW_lin  = wc + woff[4];  float* cW_edge = wc + woff[5];
  float* catt_s  = wc + woff[6];  float* catt_d  = wc + woff[7];
  float* catt_e  = wc + woff[8];  float* cbconv  = wc + woff[9];
  float* cgamma  = wc + woff[10]; float* cbeta   = wc + woff[11];
  float* cW_out  = wc + woff[12]; float* cb_out  = wc + woff[13];

  hipMemsetAsync(deg, 0, zbytes, stream);
  prep<<<256, 256, 0, stream>>>(L, x, xc, N*16, dflag);
  precompute_M<<<1, 256, 0, stream>>>(cW_edge, catt_e, cW_bond, cb_bond, Mmat, cbias);
  deg_count<<<(E + 255)/256, 256, 0, stream>>>(ei, E, deg);
  int P = (N + 1023)/1024;
  scan_part<<<P, 256, 0, stream>>>(deg, part, N);
  scan_top<<<1, 64, 0, stream>>>(part, P);
  scan_write<<<P, 256, 0, stream>>>(deg, part, row, N, E);
  csr_fill<<<(E + 255)/256, 256, 0, stream>>>(ei, E, row, cursor, eattr, rec, dflag);
  ea_mean_k<<<(N*4 + 255)/256, 256, 0, stream>>>((const unsigned int*)rec, row, ea_mean, deg_ind, N);

  // atom embedding: hA(fp32) + hAb(bf16) = x @ W_atom + b_atom
  mfma_lin<64, 2, false><<<(N + 63)/64, 256, 0, stream>>>(xc, cW_atom, cb_atom, hA, hAb, N,
      nullptr, nullptr, nullptr, nullptr, nullptr, nullptr, nullptr, nullptr, nullptr);
  // layer-0 GEMM + attention scores + self-loop alpha
  mfma_lin<128, 0, true><<<(N + 63)/64, 256, 0, stream>>>(hAb, cW_lin, nullptr, xhb, nullptr, N,
      catt_s, catt_d, Mmat, cbias, ea_mean, deg_ind, a_src, a_dst, alphaS);

  float* cur = hA; float* oth = hB;
  for (int l = 0; l < 3; ++l){
    edge_alpha<<<(E + 255)/256, 256, 0, stream>>>(rec, a_src, a_dst, Mmat, cbias,
                                                  alphaA, srcA, E, l);
    gat_agg<<<(N + 3)/4, 256, 0, stream>>>(xhb, alphaA, srcA, row, (const float4*)alphaS,
                                           cbconv, hG, N, l);
    bn_stats<<<256, 256, 0, stream>>>(hG, bnsum + l*128, bnsq + l*128, N);
    if (l < 2){
      bn_mfma<0, true><<<(N + 63)/64, 256, 0, stream>>>(hG, cur,
          bnsum + l*128, bnsq + l*128, cgamma + l*128, cbeta + l*128,
          cW_lin + (size_t)(l+1)*16384, nullptr, xhb, oth, N, dflag,
          catt_s + (l+1)*128, catt_d + (l+1)*128, Mmat + (l+1)*4, cbias + (l+1)*4,
          ea_mean, deg_ind, a_src, a_dst, alphaS);
      float* t = cur; cur = oth; oth = t;
    } else {
      bn_mfma<1, false><<<(N + 63)/64, 256, 0, stream>>>(hG, cur,
          bnsum + l*128, bnsq + l*128, cgamma + l*128, cbeta + l*128,
          cW_out, cb_out, d_out, nullptr, N, dflag,
          nullptr, nullptr, nullptr, nullptr, nullptr, nullptr, nullptr, nullptr, nullptr);
    }
  }
}

// Round 9
// 610.089 us; speedup vs baseline: 1.6040x; 1.0085x over previous
//
#include <hip/hip_runtime.h>
#include <stdint.h>

#define HID 128

typedef __attribute__((ext_vector_type(8))) short bf16x8;
typedef __attribute__((ext_vector_type(4))) float f32x4;

__device__ __forceinline__ float bf2f(unsigned short u){
  union { unsigned int i; float f; } x; x.i = ((unsigned int)u) << 16; return x.f;
}
__device__ __forceinline__ unsigned short f2bf(float f){
  union { float f; unsigned int i; } x; x.f = f;
  unsigned int b = x.i;
  return (unsigned short)((b + 0x7fffu + ((b >> 16) & 1u)) >> 16);
}

// ---------------- setup: dtype flag + weight conv + x->bf16 + deg_count ----------
struct CvList {
  const void* src[16];
  float* dst[16];
  int cnt[16];
  int n;
};
__global__ __launch_bounds__(256) void setup(CvList L, const void* x,
                                             unsigned short* xc, int n4,
                                             int* __restrict__ dflag,
                                             const int* __restrict__ ei, int E,
                                             int* __restrict__ deg){
  __shared__ int red[4];
  int tid = threadIdx.x;
  const unsigned short* xs = (const unsigned short*)x;
  unsigned short u = xs[tid];
  int ex = (u >> 7) & 0xFF;
  int v = ((((tid & 1) == 0) && u == 0) ? 1 : 0) | ((ex >= 140) ? 65536 : 0);
  #pragma unroll
  for (int m = 1; m < 64; m <<= 1) v += __shfl_xor(v, m);
  if ((tid & 63) == 0) red[tid >> 6] = v;
  __syncthreads();
  int tot = red[0] + red[1] + red[2] + red[3];
  bool isf32 = ((tot & 0xffff) >= 32) || ((tot >> 16) >= 8);
  if (blockIdx.x == 0 && tid == 0) dflag[0] = isf32 ? 1 : 0;
  // degree count (whole grid)
  int e = blockIdx.x*256 + tid;
  if (e < E) atomicAdd(&deg[ei[E + e]], 1);
  // weights + x conversion (first 256 blocks)
  if (blockIdx.x < 256){
    for (int a = 0; a < L.n; ++a){
      const void* s = L.src[a];
      float* d = L.dst[a];
      int c = L.cnt[a];
      for (int i = blockIdx.x*256 + tid; i < c; i += 65536)
        d[i] = isf32 ? ((const float*)s)[i] : bf2f(((const unsigned short*)s)[i]);
    }
    for (int i = blockIdx.x*256 + tid; i < n4; i += 65536){
      if (isf32){
        float4 q = ((const float4*)x)[i];
        ushort4 o; o.x = f2bf(q.x); o.y = f2bf(q.y); o.z = f2bf(q.z); o.w = f2bf(q.w);
        ((ushort4*)xc)[i] = o;
      } else {
        ((ushort4*)xc)[i] = ((const ushort4*)x)[i];
      }
    }
  }
}

// ---------------- precompute M = W_bond @ (W_edge @ att_edge), cbias = b_bond @ ve ----
__global__ __launch_bounds__(256) void precompute_M(
    const float* __restrict__ We, const float* __restrict__ ae,
    const float* __restrict__ Wb, const float* __restrict__ bb,
    float* __restrict__ Mout, float* __restrict__ cb)
{
  __shared__ float ve[128*12];
  int tid = threadIdx.x;
  for (int i = tid; i < 128*12; i += 256){
    int c = i / 12, lh = i % 12; int l = lh >> 2, h = lh & 3;
    float s = 0.f;
    for (int d = 0; d < 32; ++d)
      s += We[l*16384 + c*128 + h*32 + d] * ae[l*128 + h*32 + d];
    ve[i] = s;
  }
  __syncthreads();
  for (int i = tid; i < 16*12; i += 256){
    int k = i / 12, lh = i % 12;
    float s = 0.f;
    for (int c = 0; c < 128; ++c) s += Wb[k*128 + c] * ve[c*12 + lh];
    Mout[i] = s;
  }
  for (int i = tid; i < 12; i += 256){
    float s = 0.f;
    for (int c = 0; c < 128; ++c) s += bb[c] * ve[c*12 + i];
    cb[i] = s;
  }
}

// ---------------- CSR build ----------------
__global__ __launch_bounds__(256) void scan_part(const int* __restrict__ deg, int* __restrict__ part, int N){
  int base = blockIdx.x*1024;
  int s = 0;
  for (int i = threadIdx.x; i < 1024; i += 256){ int j = base + i; if (j < N) s += deg[j]; }
  __shared__ int sh[256];
  sh[threadIdx.x] = s; __syncthreads();
  for (int m = 128; m > 0; m >>= 1){ if (threadIdx.x < m) sh[threadIdx.x] += sh[threadIdx.x + m]; __syncthreads(); }
  if (threadIdx.x == 0) part[blockIdx.x] = sh[0];
}
__global__ void scan_top(int* part, int P){
  if (threadIdx.x == 0 && blockIdx.x == 0){
    int acc = 0;
    for (int i = 0; i < P; ++i){ int v = part[i]; part[i] = acc; acc += v; }
  }
}
__global__ __launch_bounds__(256) void scan_write(const int* __restrict__ deg, const int* __restrict__ part,
                                                  int* __restrict__ row, int N, int E){
  int base = blockIdx.x*1024 + threadIdx.x*4;
  int v0=0,v1=0,v2=0,v3=0;
  if (base+0 < N) v0 = deg[base+0];
  if (base+1 < N) v1 = deg[base+1];
  if (base+2 < N) v2 = deg[base+2];
  if (base+3 < N) v3 = deg[base+3];
  int s = v0+v1+v2+v3;
  __shared__ int sh[256];
  sh[threadIdx.x] = s; __syncthreads();
  for (int m = 1; m < 256; m <<= 1){
    int t = (threadIdx.x >= m) ? sh[threadIdx.x - m] : 0;
    __syncthreads();
    sh[threadIdx.x] += t;
    __syncthreads();
  }
  int excl = sh[threadIdx.x] - s + part[blockIdx.x];
  if (base+0 < N) row[base+0] = excl; excl += v0;
  if (base+1 < N) row[base+1] = excl; excl += v1;
  if (base+2 < N) row[base+2] = excl; excl += v2;
  if (base+3 < N) row[base+3] = excl;
  if (blockIdx.x == 0 && threadIdx.x == 0) row[N] = E;
}
// CSR fill + edge_attr reorder: ONE full 64 B record per edge (write-combined line)
__global__ __launch_bounds__(256) void csr_fill(const int* __restrict__ ei, int E,
                                                const int* __restrict__ row, int* __restrict__ cursor,
                                                const void* __restrict__ eattr,
                                                uint4* __restrict__ rec, const int* __restrict__ flag){
  int e = blockIdx.x*256 + threadIdx.x;
  if (e >= E) return;
  int s = ei[e], d = ei[E + e];
  uint4 q0, q1;
  if (flag[0]){
    const float4* pp = (const float4*)((const float*)eattr + (size_t)e*16);
    float4 a = pp[0], b = pp[1], c = pp[2], dd = pp[3];
    q0.x = f2bf(a.x) | ((unsigned)f2bf(a.y) << 16);
    q0.y = f2bf(a.z) | ((unsigned)f2bf(a.w) << 16);
    q0.z = f2bf(b.x) | ((unsigned)f2bf(b.y) << 16);
    q0.w = f2bf(b.z) | ((unsigned)f2bf(b.w) << 16);
    q1.x = f2bf(c.x) | ((unsigned)f2bf(c.y) << 16);
    q1.y = f2bf(c.z) | ((unsigned)f2bf(c.w) << 16);
    q1.z = f2bf(dd.x) | ((unsigned)f2bf(dd.y) << 16);
    q1.w = f2bf(dd.z) | ((unsigned)f2bf(dd.w) << 16);
  } else {
    const uint4* pp = (const uint4*)((const unsigned short*)eattr + (size_t)e*16);
    q0 = pp[0]; q1 = pp[1];
  }
  int pos = atomicAdd(&cursor[d], 1);
  size_t idx = (size_t)(row[d] + pos);
  uint4* rp = rec + idx*4;
  uint4 q2; q2.x = (unsigned)s; q2.y = (unsigned)d; q2.z = 0u; q2.w = 0u;
  uint4 q3; q3.x = 0u; q3.y = 0u; q3.z = 0u; q3.w = 0u;
  rp[0] = q0; rp[1] = q1; rp[2] = q2; rp[3] = q3;   // full 64 B line
}
// per-node mean of CSR-ordered edge_attr (layer-invariant), + deg indicator
__global__ __launch_bounds__(256) void ea_mean_k(const unsigned int* __restrict__ rec,
                                                 const int* __restrict__ row,
                                                 float* __restrict__ ea_mean,
                                                 float* __restrict__ deg_ind, int N){
  int idx = blockIdx.x*256 + threadIdx.x;
  if (idx >= N*4) return;
  int n = idx >> 2, q = idx & 3;
  int r = row[n], deg = row[n+1] - r;
  float s0=0.f, s1=0.f, s2=0.f, s3=0.f;
  for (int e = 0; e < deg; ++e){
    uint2 u = *(const uint2*)(rec + (size_t)(r+e)*16 + q*2);
    s0 += bf2f((unsigned short)(u.x & 0xffffu)); s1 += bf2f((unsigned short)(u.x >> 16));
    s2 += bf2f((unsigned short)(u.y & 0xffffu)); s3 += bf2f((unsigned short)(u.y >> 16));
  }
  float inv = 1.f / (float)(deg > 0 ? deg : 1);
  float4 o; o.x = s0*inv; o.y = s1*inv; o.z = s2*inv; o.w = s3*inv;
  *(float4*)(ea_mean + (size_t)n*16 + q*4) = o;
  if (q == 0) deg_ind[n] = (deg > 0) ? 1.f : 0.f;
}

__device__ __forceinline__ float lrelu(float x){ return x > 0.f ? x : 0.2f*x; }
__device__ __forceinline__ float expg(float x){ return __expf(fminf(x, 0.f)); }

// shared EPI: attention scores + self-loop alpha, from acc[8] C-fragments
template<typename ACC>
__device__ __forceinline__ void att_epi(const ACC* acc, int m, int quad, int nodeBase, int N,
                                        const float* sAs, const float* sAd,
                                        const float (*sMM)[4], const float* sCB,
                                        const float* __restrict__ ea_mean,
                                        const float* __restrict__ deg_ind,
                                        float* __restrict__ a_src,
                                        float* __restrict__ a_dst,
                                        float* __restrict__ alpha_self)
{
  #pragma unroll
  for (int r2 = 0; r2 < 4; ++r2){
    float vs[4], vd[4];
    #pragma unroll
    for (int h = 0; h < 4; ++h){
      int c0 = (2*h)*16 + m, c1 = (2*h+1)*16 + m;
      vs[h] = acc[2*h][r2]*sAs[c0] + acc[2*h+1][r2]*sAs[c1];
      vd[h] = acc[2*h][r2]*sAd[c0] + acc[2*h+1][r2]*sAd[c1];
    }
    #pragma unroll
    for (int mm = 1; mm < 16; mm <<= 1){
      #pragma unroll
      for (int h = 0; h < 4; ++h){
        vs[h] += __shfl_xor(vs[h], mm);
        vd[h] += __shfl_xor(vd[h], mm);
      }
    }
    if (m == 0){
      int nd = nodeBase + quad*4 + r2;
      if (nd < N){
        float ci = deg_ind[nd];
        const float4* em = (const float4*)(ea_mean + (size_t)nd*16);
        float4 e0 = em[0], e1 = em[1], e2 = em[2], e3 = em[3];
        float ev[16] = {e0.x,e0.y,e0.z,e0.w, e1.x,e1.y,e1.z,e1.w,
                        e2.x,e2.y,e2.z,e2.w, e3.x,e3.y,e3.z,e3.w};
        float aS[4];
        #pragma unroll
        for (int h = 0; h < 4; ++h){
          float d = sCB[h]*ci;
          #pragma unroll
          for (int k = 0; k < 16; ++k) d += ev[k]*sMM[k][h];
          aS[h] = lrelu(vs[h] + vd[h] + d);
        }
        float4 vsv, vdv, asv;
        vsv.x=vs[0]; vsv.y=vs[1]; vsv.z=vs[2]; vsv.w=vs[3];
        vdv.x=vd[0]; vdv.y=vd[1]; vdv.z=vd[2]; vdv.w=vd[3];
        asv.x=aS[0]; asv.y=aS[1]; asv.z=aS[2]; asv.w=aS[3];
        *(float4*)(a_src + (size_t)nd*4) = vsv;
        *(float4*)(a_dst + (size_t)nd*4) = vdv;
        *(float4*)(alpha_self + (size_t)nd*4) = asv;
      }
    }
  }
}

// ---------------- MFMA GEMM: out[N,128] = A[N,K](bf16) @ W[K,128] (+bias) ----------------
// OUTMODE: 0 = bf16 out (+EPI), 2 = dual fp32 + bf16 (no EPI)
template<int K, int OUTMODE, bool EPI>
__global__ __launch_bounds__(256) void mfma_lin(const unsigned short* __restrict__ A,
                                                const float* __restrict__ W,
                                                const float* __restrict__ bias,
                                                void* __restrict__ Out, void* __restrict__ Out2,
                                                int N,
                                                const float* __restrict__ attS,
                                                const float* __restrict__ attD,
                                                const float* __restrict__ Ml,
                                                const float* __restrict__ cbl,
                                                const float* __restrict__ ea_mean,
                                                const float* __restrict__ deg_ind,
                                                float* __restrict__ a_src,
                                                float* __restrict__ a_dst,
                                                float* __restrict__ alpha_self)
{
  constexpr int KP = K + 8;
  __shared__ unsigned short WT[128*KP];
  __shared__ float sAs[128], sAd[128];
  __shared__ float sMM[16][4];
  __shared__ float sCB[4];
  int tid = threadIdx.x;
  for (int i = tid; i < K*128; i += 256){
    int k = i >> 7, ch = i & 127;
    WT[ch*KP + k] = f2bf(W[i]);
  }
  if (EPI){
    if (tid < 128){ sAs[tid] = attS[tid]; sAd[tid] = attD[tid]; }
    if (tid < 64) sMM[tid>>2][tid&3] = Ml[(tid>>2)*12 + (tid&3)];
    if (tid < 4)  sCB[tid] = cbl[tid];
  }
  __syncthreads();
  int wid = tid >> 6, lane = tid & 63;
  int quad = lane >> 4, m = lane & 15;
  int nodeBase = blockIdx.x*64 + wid*16;
  int node = nodeBase + m;
  int nodeC = (node < N) ? node : 0;
  bf16x8 afr[K/32];
  #pragma unroll
  for (int kb = 0; kb < K/32; ++kb)
    afr[kb] = *(const bf16x8*)(A + (size_t)nodeC*K + kb*32 + quad*8);
  f32x4 acc[8] = {};
  #pragma unroll
  for (int t = 0; t < 8; ++t){
    #pragma unroll
    for (int kb = 0; kb < K/32; ++kb){
      bf16x8 bfr = *(const bf16x8*)&WT[(t*16 + m)*KP + kb*32 + quad*8];
      acc[t] = __builtin_amdgcn_mfma_f32_16x16x32_bf16(afr[kb], bfr, acc[t], 0, 0, 0);
    }
  }
  #pragma unroll
  for (int t = 0; t < 8; ++t){
    int ch = t*16 + m;
    float bv = bias ? bias[ch] : 0.f;
    #pragma unroll
    for (int r2 = 0; r2 < 4; ++r2){
      int nd = nodeBase + quad*4 + r2;
      if (nd < N){
        float v = acc[t][r2] + bv;
        if (OUTMODE == 0){
          ((unsigned short*)Out)[(size_t)nd*HID + ch] = f2bf(v);
        } else {
          ((float*)Out)[(size_t)nd*HID + ch] = v;
          ((unsigned short*)Out2)[(size_t)nd*HID + ch] = f2bf(v);
        }
      }
    }
  }
  if (EPI)
    att_epi(acc, m, quad, nodeBase, N, sAs, sAd, sMM, sCB,
            ea_mean, deg_ind, a_src, a_dst, alpha_self);
}

// ---------------- fused BN + ReLU + residual + GEMM (+EPI / external out) -------------
// hg is bf16 (GAT output). OUTMODE 0: bf16 xh out + EPI + fp32 h out; 1: external out
template<int OUTMODE, bool WRITEH>
__global__ __launch_bounds__(256) void bn_mfma(const unsigned short* __restrict__ hg,
                                               const float* __restrict__ hprev,
                                               const float* __restrict__ bnsum,
                                               const float* __restrict__ bnsq,
                                               const float* __restrict__ gamma,
                                               const float* __restrict__ beta,
                                               const float* __restrict__ W,
                                               const float* __restrict__ bias,
                                               void* __restrict__ Out,
                                               float* __restrict__ hout,
                                               int N, const int* __restrict__ flag,
                                               const float* __restrict__ attS,
                                               const float* __restrict__ attD,
                                               const float* __restrict__ Ml,
                                               const float* __restrict__ cbl,
                                               const float* __restrict__ ea_mean,
                                               const float* __restrict__ deg_ind,
                                               float* __restrict__ a_src,
                                               float* __restrict__ a_dst,
                                               float* __restrict__ alpha_self)
{
  constexpr int K = 128, KP = 136;
  __shared__ unsigned short WT[128*KP];
  __shared__ float sSc[128], sSh[128];
  __shared__ float sAs[128], sAd[128];
  __shared__ float sMM[16][4];
  __shared__ float sCB[4];
  int tid = threadIdx.x;
  for (int i = tid; i < K*128; i += 256){
    int k = i >> 7, ch = i & 127;
    WT[ch*KP + k] = f2bf(W[i]);
  }
  if (tid < 128){
    float mean = bnsum[tid] / (float)N;
    float var  = fmaxf(bnsq[tid] / (float)N - mean*mean, 0.f);
    float sc = gamma[tid] * rsqrtf(var + 1e-5f);
    sSc[tid] = sc;
    sSh[tid] = beta[tid] - mean*sc;
    if (OUTMODE == 0){ sAs[tid] = attS[tid]; sAd[tid] = attD[tid]; }
  }
  if (OUTMODE == 0){
    if (tid < 64) sMM[tid>>2][tid&3] = Ml[(tid>>2)*12 + (tid&3)];
    if (tid < 4)  sCB[tid] = cbl[tid];
  }
  __syncthreads();
  int wid = tid >> 6, lane = tid & 63;
  int quad = lane >> 4, m = lane & 15;
  int nodeBase = blockIdx.x*64 + wid*16;
  int node = nodeBase + m;
  int nodeC = (node < N) ? node : 0;
  bf16x8 afr[4];
  #pragma unroll
  for (int kb = 0; kb < 4; ++kb){
    int cbase = kb*32 + quad*8;
    uint4 gu = *(const uint4*)(hg + (size_t)nodeC*K + cbase);
    const float4* pp = (const float4*)(hprev + (size_t)nodeC*K + cbase);
    float4 p0 = pp[0], p1 = pp[1];
    unsigned gw[4] = {gu.x, gu.y, gu.z, gu.w};
    float pv[8] = {p0.x,p0.y,p0.z,p0.w,p1.x,p1.y,p1.z,p1.w};
    float r[8];
    #pragma unroll
    for (int j = 0; j < 8; ++j){
      float g = bf2f((unsigned short)((j & 1) ? (gw[j>>1] >> 16) : (gw[j>>1] & 0xffffu)));
      float t = g*sSc[cbase+j] + sSh[cbase+j];
      t = t > 0.f ? t : 0.f;
      r[j] = t + pv[j];
    }
    if (WRITEH && node < N){
      float4 o0, o1;
      o0.x=r[0]; o0.y=r[1]; o0.z=r[2]; o0.w=r[3];
      o1.x=r[4]; o1.y=r[5]; o1.z=r[6]; o1.w=r[7];
      float4* hp = (float4*)(hout + (size_t)node*K + cbase);
      hp[0] = o0; hp[1] = o1;
    }
    bf16x8 f;
    #pragma unroll
    for (int j = 0; j < 8; ++j) f[j] = (short)f2bf(r[j]);
    afr[kb] = f;
  }
  f32x4 acc[8] = {};
  #pragma unroll
  for (int t = 0; t < 8; ++t){
    #pragma unroll
    for (int kb = 0; kb < 4; ++kb){
      bf16x8 bfr = *(const bf16x8*)&WT[(t*16 + m)*KP + kb*32 + quad*8];
      acc[t] = __builtin_amdgcn_mfma_f32_16x16x32_bf16(afr[kb], bfr, acc[t], 0, 0, 0);
    }
  }
  bool f32out = (OUTMODE == 1) && (flag[0] != 0);
  #pragma unroll
  for (int t = 0; t < 8; ++t){
    int ch = t*16 + m;
    float bv = bias ? bias[ch] : 0.f;
    #pragma unroll
    for (int r2 = 0; r2 < 4; ++r2){
      int nd = nodeBase + quad*4 + r2;
      if (nd < N){
        float v = acc[t][r2] + bv;
        if (OUTMODE == 0) ((unsigned short*)Out)[(size_t)nd*HID + ch] = f2bf(v);
        else if (f32out)  ((float*)Out)[(size_t)nd*HID + ch] = v;
        else              ((unsigned short*)Out)[(size_t)nd*HID + ch] = f2bf(v);
      }
    }
  }
  if (OUTMODE == 0)
    att_epi(acc, m, quad, nodeBase, N, sAs, sAd, sMM, sCB,
            ea_mean, deg_ind, a_src, a_dst, alpha_self);
}

// ---------------- edge-parallel alpha (coalesced records -> bf16 alpha) ----------
__global__ __launch_bounds__(256) void edge_alpha(
    const uint4* __restrict__ rec,
    const float* __restrict__ a_src, const float* __restrict__ a_dst,
    const float* __restrict__ Mmat, const float* __restrict__ cbias,
    ushort4* __restrict__ alphaA, int* __restrict__ srcA, int E, int layer)
{
  __shared__ float sM[16][4];
  __shared__ float sC[4];
  int tid = threadIdx.x;
  if (tid < 64) sM[tid>>2][tid&3] = Mmat[(tid>>2)*12 + layer*4 + (tid&3)];
  if (tid < 4)  sC[tid] = cbias[layer*4 + tid];
  __syncthreads();
  int pos = blockIdx.x*256 + tid;
  if (pos >= E) return;
  const uint4* rp = rec + (size_t)pos*4;
  uint4 u0 = rp[0], u1 = rp[1], u2 = rp[2];
  int src = (int)u2.x, dst = (int)u2.y;
  unsigned w[8] = {u0.x,u0.y,u0.z,u0.w,u1.x,u1.y,u1.z,u1.w};
  float a0 = sC[0], a1 = sC[1], a2 = sC[2], a3 = sC[3];
  #pragma unroll
  for (int k = 0; k < 16; ++k){
    float v = bf2f((unsigned short)((k & 1) ? (w[k>>1] >> 16) : (w[k>>1] & 0xffffu)));
    a0 += v*sM[k][0]; a1 += v*sM[k][1]; a2 += v*sM[k][2]; a3 += v*sM[k][3];
  }
  float4 as4 = *(const float4*)(a_src + (size_t)src*4);
  float4 ad4 = *(const float4*)(a_dst + (size_t)dst*4);
  ushort4 al;
  al.x = f2bf(lrelu(as4.x + ad4.x + a0));
  al.y = f2bf(lrelu(as4.y + ad4.y + a1));
  al.z = f2bf(lrelu(as4.z + ad4.z + a2));
  al.w = f2bf(lrelu(as4.w + ad4.w + a3));
  alphaA[pos] = al;
  srcA[pos] = src;
}

// ---------------- GAT aggregation: wave/node, bf16 alpha + bf16 gathers, bf16 out ----
__global__ __launch_bounds__(256) void gat_agg(
    const unsigned short* __restrict__ xh, const ushort4* __restrict__ alphaA,
    const int* __restrict__ srcA, const int* __restrict__ row,
    const float4* __restrict__ alpha_self,
    const float* __restrict__ bconv, unsigned short* __restrict__ hout, int N, int layer)
{
  __shared__ float sPf[4][256];   // [wave][e*4+h]  (conflict-free reads)
  __shared__ int   sOff[4][64];
  int tid = threadIdx.x;
  int wid = tid >> 6, lane = tid & 63;
  int n = blockIdx.x*4 + wid;
  int nn = (n < N) ? n : 0;
  int r = row[nn];
  int deg = row[nn+1] - r;
  if (n >= N) deg = 0;

  float4 aL; aL.x = aL.y = aL.z = aL.w = -1e30f;
  int mysrc = 0;
  if (lane < deg){
    ushort4 ap = alphaA[r + lane];
    aL.x = bf2f(ap.x); aL.y = bf2f(ap.y); aL.z = bf2f(ap.z); aL.w = bf2f(ap.w);
    mysrc = srcA[r + lane];
  }
  float mx0 = aL.x, mx1 = aL.y, mx2 = aL.z, mx3 = aL.w;
  for (int e = lane + 64; e < deg; e += 64){   // rare
    ushort4 ap = alphaA[r + e];
    mx0 = fmaxf(mx0, bf2f(ap.x)); mx1 = fmaxf(mx1, bf2f(ap.y));
    mx2 = fmaxf(mx2, bf2f(ap.z)); mx3 = fmaxf(mx3, bf2f(ap.w));
  }
  #pragma unroll
  for (int m = 1; m < 64; m <<= 1){
    mx0 = fmaxf(mx0, __shfl_xor(mx0,m)); mx1 = fmaxf(mx1, __shfl_xor(mx1,m));
    mx2 = fmaxf(mx2, __shfl_xor(mx2,m)); mx3 = fmaxf(mx3, __shfl_xor(mx3,m));
  }
  float4 sf = alpha_self[nn];
  mx0 = fmaxf(mx0, sf.x); mx1 = fmaxf(mx1, sf.y);
  mx2 = fmaxf(mx2, sf.z); mx3 = fmaxf(mx3, sf.w);

  float p0 = 0.f, p1 = 0.f, p2 = 0.f, p3 = 0.f;
  if (lane < deg){
    p0 = expg(aL.x-mx0); p1 = expg(aL.y-mx1);
    p2 = expg(aL.z-mx2); p3 = expg(aL.w-mx3);
  }
  float4 pv; pv.x = p0; pv.y = p1; pv.z = p2; pv.w = p3;
  *(float4*)&sPf[wid][lane*4] = pv;
  sOff[wid][lane] = mysrc << 8;   // src * 256 B (bf16 row)
  float d0 = p0, d1 = p1, d2 = p2, d3 = p3;
  for (int e = lane + 64; e < deg; e += 64){   // rare
    ushort4 ap = alphaA[r + e];
    d0 += expg(bf2f(ap.x)-mx0); d1 += expg(bf2f(ap.y)-mx1);
    d2 += expg(bf2f(ap.z)-mx2); d3 += expg(bf2f(ap.w)-mx3);
  }
  #pragma unroll
  for (int m = 1; m < 64; m <<= 1){
    d0 += __shfl_xor(d0,m); d1 += __shfl_xor(d1,m); d2 += __shfl_xor(d2,m); d3 += __shfl_xor(d3,m);
  }
  float ps0 = expg(sf.x-mx0), ps1 = expg(sf.y-mx1), ps2 = expg(sf.z-mx2), ps3 = expg(sf.w-mx3);
  float i0 = 1.0f/(d0+ps0+1e-16f), i1 = 1.0f/(d1+ps1+1e-16f);
  float i2 = 1.0f/(d2+ps2+1e-16f), i3 = 1.0f/(d3+ps3+1e-16f);

  // gather: lane covers channels 2*lane, 2*lane+1; head h = lane>>4
  int h = lane >> 4;
  float psh = h==0 ? ps0 : h==1 ? ps1 : h==2 ? ps2 : ps3;
  float ih  = h==0 ? i0  : h==1 ? i1  : h==2 ? i2  : i3;
  float mxh = h==0 ? mx0 : h==1 ? mx1 : h==2 ? mx2 : mx3;
  const char* xb = (const char*)xh;
  float acc0 = 0.f, acc1 = 0.f;
  int dmin = deg < 64 ? deg : 64;
  int e = 0;
  for (; e + 4 <= dmin; e += 4){
    int oA = sOff[wid][e+0], oB = sOff[wid][e+1], oC = sOff[wid][e+2], oD = sOff[wid][e+3];
    float qA = sPf[wid][(e+0)*4 + h], qB = sPf[wid][(e+1)*4 + h];
    float qC = sPf[wid][(e+2)*4 + h], qD = sPf[wid][(e+3)*4 + h];
    ushort2 xA = *(const ushort2*)(xb + (size_t)oA + lane*4);
    ushort2 xB = *(const ushort2*)(xb + (size_t)oB + lane*4);
    ushort2 xC = *(const ushort2*)(xb + (size_t)oC + lane*4);
    ushort2 xD = *(const ushort2*)(xb + (size_t)oD + lane*4);
    acc0 += qA*bf2f(xA.x) + qB*bf2f(xB.x) + qC*bf2f(xC.x) + qD*bf2f(xD.x);
    acc1 += qA*bf2f(xA.y) + qB*bf2f(xB.y) + qC*bf2f(xC.y) + qD*bf2f(xD.y);
  }
  for (; e < dmin; ++e){
    int o = sOff[wid][e];
    float q = sPf[wid][e*4 + h];
    ushort2 xv = *(const ushort2*)(xb + (size_t)o + lane*4);
    acc0 += q*bf2f(xv.x); acc1 += q*bf2f(xv.y);
  }
  for (; e < deg; ++e){            // rare (deg>64)
    ushort4 ap = alphaA[r + e];
    float av = h==0 ? bf2f(ap.x) : h==1 ? bf2f(ap.y) : h==2 ? bf2f(ap.z) : bf2f(ap.w);
    float q = expg(av - mxh);
    int s = srcA[r + e];
    ushort2 xv = *(const ushort2*)(xb + (size_t)s*256 + lane*4);
    acc0 += q*bf2f(xv.x); acc1 += q*bf2f(xv.y);
  }
  if (n < N){
    ushort2 xn = *(const ushort2*)(xb + (size_t)nn*256 + lane*4);
    acc0 += psh * bf2f(xn.x);
    acc1 += psh * bf2f(xn.y);
    float2 bc = *(const float2*)(bconv + layer*128 + 2*lane);
    acc0 = acc0*ih + bc.x;
    acc1 = acc1*ih + bc.y;
    ushort2 o; o.x = f2bf(acc0); o.y = f2bf(acc1);
    *(ushort2*)(hout + (size_t)nn*128 + 2*lane) = o;
  }
}

// ---------------- batch norm stats (bf16 input) ----------------
__global__ __launch_bounds__(256) void bn_stats(const unsigned short* __restrict__ h,
                                                float* __restrict__ sum,
                                                float* __restrict__ sq, int N){
  int c = threadIdx.x & 127;
  int sub = threadIdx.x >> 7;
  float s = 0.f, q = 0.f;
  for (int n = blockIdx.x*2 + sub; n < N; n += gridDim.x*2){
    float v = bf2f(h[(size_t)n*128 + c]);
    s += v; q += v*v;
  }
  __shared__ float ls[256], lq[256];
  ls[threadIdx.x] = s; lq[threadIdx.x] = q;
  __syncthreads();
  if (threadIdx.x < 128){
    s = ls[threadIdx.x] + ls[threadIdx.x + 128];
    q = lq[threadIdx.x] + lq[threadIdx.x + 128];
    atomicAdd(&sum[c], s);
    atomicAdd(&sq[c], q);
  }
}

// ---------------- host ----------------
extern "C" void kernel_launch(void* const* d_in, const int* in_sizes, int n_in,
                              void* d_out, int out_size, void* d_ws, size_t ws_size,
                              hipStream_t stream)
{
  const void* x        = d_in[0];
  const int*  ei       = (const int*)d_in[1];
  const void* eattr    = d_in[2];
  int N = in_sizes[0] / 64;
  int E = in_sizes[1] / 2;

  char* p = (char*)d_ws;
  auto alloc = [&](size_t bytes)->char* {
    char* r = p; p += (bytes + 255) & ~(size_t)255; return r;
  };
  // zero-region first (one memset)
  int*   deg    = (int*)alloc((size_t)N*4);
  int*   cursor = (int*)alloc((size_t)N*4);
  float* bnsum  = (float*)alloc(3*128*4);
  float* bnsq   = (float*)alloc(3*128*4);
  size_t zbytes = (size_t)(p - (char*)deg);
  int*   dflag  = (int*)alloc(256);
  int*   row    = (int*)alloc(((size_t)N + 1)*4);
  int*   part   = (int*)alloc(1024*4);
  uint4* rec    = (uint4*)alloc((size_t)E*64);
  int*   srcA   = (int*)alloc((size_t)E*4);
  ushort4* alphaA = (ushort4*)alloc((size_t)E*8);
  float* hA     = (float*)alloc((size_t)N*128*4);
  float* hB     = (float*)alloc((size_t)N*128*4);
  unsigned short* hGb = (unsigned short*)alloc((size_t)N*128*2);
  unsigned short* hAb = (unsigned short*)alloc((size_t)N*128*2);
  unsigned short* xhb = (unsigned short*)alloc((size_t)N*128*2);
  float* a_src  = (float*)alloc((size_t)N*4*4);
  float* a_dst  = (float*)alloc((size_t)N*4*4);
  float* alphaS = (float*)alloc((size_t)N*4*4);
  float* ea_mean= (float*)alloc((size_t)N*16*4);
  float* deg_ind= (float*)alloc((size_t)N*4);
  float* Mmat   = (float*)alloc(16*12*4);
  float* cbias  = (float*)alloc(12*4);
  unsigned short* xc  = (unsigned short*)alloc((size_t)N*64*2);
  float* wc     = (float*)alloc(130000*4);

  // canonical weight buffers (fp32)
  int   woff[14] = {0, 8192, 8320, 10368, 10496, 59648, 108800, 109184,
                    109568, 109952, 110336, 110720, 111104, 127488};
  int   wcnt[14] = {8192, 128, 2048, 128, 49152, 49152, 384, 384, 384, 384, 384, 384, 16384, 128};
  CvList L; L.n = 14;
  for (int a = 0; a < 14; ++a){ L.src[a] = d_in[3+a]; L.dst[a] = wc + woff[a]; L.cnt[a] = wcnt[a]; }
  float* cW_atom = wc + woff[0];  float* cb_atom = wc + woff[1];
  float* cW_bond = wc + woff[2];  float* cb_bond = wc + woff[3];
  float* cW_lin  = wc + woff[4];  float* cW_edge = wc + woff[5];
  float* catt_s  = wc + woff[6];  float* catt_d  = wc + woff[7];
  float* catt_e  = wc + woff[8];  float* cbconv  = wc + woff[9];
  float* cgamma  = wc + woff[10]; float* cbeta   = wc + woff[11];
  float* cW_out  = wc + woff[12]; float* cb_out  = wc + woff[13];

  hipMemsetAsync(deg, 0, zbytes, stream);
  setup<<<(E + 255)/256, 256, 0, stream>>>(L, x, xc, N*16, dflag, ei, E, deg);
  precompute_M<<<1, 256, 0, stream>>>(cW_edge, catt_e, cW_bond, cb_bond, Mmat, cbias);
  int P = (N + 1023)/1024;
  scan_part<<<P, 256, 0, stream>>>(deg, part, N);
  scan_top<<<1, 64, 0, stream>>>(part, P);
  scan_write<<<P, 256, 0, stream>>>(deg, part, row, N, E);
  csr_fill<<<(E + 255)/256, 256, 0, stream>>>(ei, E, row, cursor, eattr, rec, dflag);
  ea_mean_k<<<(N*4 + 255)/256, 256, 0, stream>>>((const unsigned int*)rec, row, ea_mean, deg_ind, N);

  // atom embedding: hA(fp32) + hAb(bf16) = x @ W_atom + b_atom
  mfma_lin<64, 2, false><<<(N + 63)/64, 256, 0, stream>>>(xc, cW_atom, cb_atom, hA, hAb, N,
      nullptr, nullptr, nullptr, nullptr, nullptr, nullptr, nullptr, nullptr, nullptr);
  // layer-0 GEMM + attention scores + self-loop alpha
  mfma_lin<128, 0, true><<<(N + 63)/64, 256, 0, stream>>>(hAb, cW_lin, nullptr, xhb, nullptr, N,
      catt_s, catt_d, Mmat, cbias, ea_mean, deg_ind, a_src, a_dst, alphaS);

  float* cur = hA; float* oth = hB;
  for (int l = 0; l < 3; ++l){
    edge_alpha<<<(E + 255)/256, 256, 0, stream>>>(rec, a_src, a_dst, Mmat, cbias,
                                                  alphaA, srcA, E, l);
    gat_agg<<<(N + 3)/4, 256, 0, stream>>>(xhb, alphaA, srcA, row, (const float4*)alphaS,
                                           cbconv, hGb, N, l);
    bn_stats<<<256, 256, 0, stream>>>(hGb, bnsum + l*128, bnsq + l*128, N);
    if (l < 2){
      bn_mfma<0, true><<<(N + 63)/64, 256, 0, stream>>>(hGb, cur,
          bnsum + l*128, bnsq + l*128, cgamma + l*128, cbeta + l*128,
          cW_lin + (size_t)(l+1)*16384, nullptr, xhb, oth, N, dflag,
          catt_s + (l+1)*128, catt_d + (l+1)*128, Mmat + (l+1)*4, cbias + (l+1)*4,
          ea_mean, deg_ind, a_src, a_dst, alphaS);
      float* t = cur; cur = oth; oth = t;
    } else {
      bn_mfma<1, false><<<(N + 63)/64, 256, 0, stream>>>(hGb, cur,
          bnsum + l*128, bnsq + l*128, cgamma + l*128, cbeta + l*128,
          cW_out, cb_out, d_out, nullptr, N, dflag,
          nullptr, nullptr, nullptr, nullptr, nullptr, nullptr, nullptr, nullptr, nullptr);
    }
  }
}